// Round 20
// baseline (629.256 us; speedup 1.0000x reference)
//
#include <hip/hip_runtime.h>
#include <hip/hip_bf16.h>

#define NU 16384
#define NI 8192
#define TOPK 10
#define NTOT (NU + NI)   // 24576
#define OCAP 64
#define NSEG 4
#define CSEG (NI / NSEG) // 2048
#define NGRP 512         // 8192 / 16 : 16-col group maxes
#define MAXSEL 16        // groups rescored per row (>=12 guaranteed coverage)

typedef short short8v __attribute__((ext_vector_type(8)));
typedef float float4v __attribute__((ext_vector_type(4)));

__device__ __forceinline__ float warp64_sum(float v) {
#pragma unroll
  for (int m = 32; m >= 1; m >>= 1) v += __shfl_xor(v, m);
  return v;
}

// monotone f32 -> u32 remap (total order preserved, exact to 1 ulp)
__device__ __forceinline__ unsigned int umap(float f) {
  unsigned int b = __float_as_uint(f);
  return b ^ ((b & 0x80000000u) ? 0xFFFFFFFFu : 0x80000000u);
}

// ---------------- fused: proj_partial(feat_v) ∪ hist ----------------
// bid < 1024: 64x64 proj tile (feat_v). bid >= 1024: hist over edges.
__global__ __launch_bounds__(256) void fused_proj_hist_kernel(
    const float* __restrict__ feat, const float* __restrict__ W,
    float* __restrict__ partial, int D, int kchunk,
    const int* __restrict__ dst, int* __restrict__ deg, int nedge) {
  __shared__ float sA[64][64];   // [k][r]
  __shared__ float sB[64][68];   // [k][c], padded
  const int tid = threadIdx.x;
  if (blockIdx.x >= 1024) {
    int e = (blockIdx.x - 1024) * 256 + tid;
    if (e < nedge) atomicAdd(&deg[dst[e]], 1);
    return;
  }
  const int pb = blockIdx.x;
  const int r0 = (pb & 127) * 64;
  const int ks = pb >> 7;
  const int rg = tid >> 4, cg = tid & 15;
  const int rA = tid & 63, kgA = (tid >> 6) * 16;
  const int kB = tid & 63, cbB = (tid >> 6) * 16;
  const int kbeg = ks * kchunk, kend = kbeg + kchunk;
  float4 pa[4], pb4[4];
  {
    const float* fp = feat + (size_t)(r0 + rA) * D + kbeg + kgA;
    pa[0] = *(const float4*)(fp + 0);  pa[1] = *(const float4*)(fp + 4);
    pa[2] = *(const float4*)(fp + 8);  pa[3] = *(const float4*)(fp + 12);
    const float* wp = W + (size_t)(kbeg + kB) * 64 + cbB;
    pb4[0] = *(const float4*)(wp + 0);  pb4[1] = *(const float4*)(wp + 4);
    pb4[2] = *(const float4*)(wp + 8);  pb4[3] = *(const float4*)(wp + 12);
  }
  float acc[4][4] = {{0,0,0,0},{0,0,0,0},{0,0,0,0},{0,0,0,0}};
  for (int kc = kbeg; kc < kend; kc += 64) {
#pragma unroll
    for (int i = 0; i < 4; ++i) {
      sA[kgA + 4*i + 0][rA] = pa[i].x;
      sA[kgA + 4*i + 1][rA] = pa[i].y;
      sA[kgA + 4*i + 2][rA] = pa[i].z;
      sA[kgA + 4*i + 3][rA] = pa[i].w;
      *(float4*)&sB[kB][cbB + 4*i] = pb4[i];
    }
    __syncthreads();
    if (kc + 64 < kend) {
      const float* fp = feat + (size_t)(r0 + rA) * D + kc + 64 + kgA;
      pa[0] = *(const float4*)(fp + 0);  pa[1] = *(const float4*)(fp + 4);
      pa[2] = *(const float4*)(fp + 8);  pa[3] = *(const float4*)(fp + 12);
      const float* wp = W + (size_t)(kc + 64 + kB) * 64 + cbB;
      pb4[0] = *(const float4*)(wp + 0);  pb4[1] = *(const float4*)(wp + 4);
      pb4[2] = *(const float4*)(wp + 8);  pb4[3] = *(const float4*)(wp + 12);
    }
#pragma unroll 8
    for (int k = 0; k < 64; ++k) {
      float4 a = *(const float4*)&sA[k][rg * 4];
      float4 b = *(const float4*)&sB[k][cg * 4];
      acc[0][0] += a.x * b.x; acc[0][1] += a.x * b.y; acc[0][2] += a.x * b.z; acc[0][3] += a.x * b.w;
      acc[1][0] += a.y * b.x; acc[1][1] += a.y * b.y; acc[1][2] += a.y * b.z; acc[1][3] += a.y * b.w;
      acc[2][0] += a.z * b.x; acc[2][1] += a.z * b.y; acc[2][2] += a.z * b.z; acc[2][3] += a.z * b.w;
      acc[3][0] += a.w * b.x; acc[3][1] += a.w * b.y; acc[3][2] += a.w * b.z; acc[3][3] += a.w * b.w;
    }
    __syncthreads();
  }
#pragma unroll
  for (int rr = 0; rr < 4; ++rr) {
    float4 o = make_float4(acc[rr][0], acc[rr][1], acc[rr][2], acc[rr][3]);
    *(float4*)(partial + ((size_t)ks * NI + r0 + rg * 4 + rr) * 64 + cg * 4) = o;
  }
}

// ---------------- fused: proj_partial(feat_t) ∪ proj_reduce_v ∪ scanA ------
// bid < 768: proj tile for feat_t (D=384, kchunk=64, -> partialT).
// 768 <= bid < 2816: reduce_v (ksplit=8 on partialV).
// bid >= 2816: scanA (96 blocks).
__global__ __launch_bounds__(256) void fused_projT_reduceV_scanA_kernel(
    const float* __restrict__ feat, const float* __restrict__ W,
    float* __restrict__ partialT,
    const float* __restrict__ partialV, const float* __restrict__ bv,
    float* __restrict__ xn, ushort* __restrict__ hi, ushort* __restrict__ lo,
    const int* __restrict__ deg, int* __restrict__ loc, int* __restrict__ bsum) {
  __shared__ float sA[64][64];
  __shared__ float sB[64][68];
  __shared__ int s[256];
  const int tid = threadIdx.x;
  const int bid = blockIdx.x;
  if (bid >= 768 && bid < 2816) {
    // ---- proj_reduce_v (ksplit = 8) ----
    const int row = (bid - 768) * 4 + (tid >> 6);
    const int col = tid & 63;
    float acc = bv[col];
#pragma unroll
    for (int ks = 0; ks < 8; ++ks)
      acc += partialV[((size_t)ks * NI + row) * 64 + col];
    float ss = warp64_sum(acc * acc);
    float v = acc * (1.0f / sqrtf(ss));
    xn[(size_t)row * 64 + col] = v;
    __hip_bfloat16 hb = __float2bfloat16(v);
    float hf = __bfloat162float(hb);
    __hip_bfloat16 lb = __float2bfloat16(v - hf);
    hi[(size_t)row * 64 + col] = *(ushort*)&hb;
    lo[(size_t)row * 64 + col] = *(ushort*)&lb;
    return;
  }
  if (bid >= 2816) {
    // ---- scanA ----
    int gid = (bid - 2816) * 256 + tid;
    int x = deg[gid];
    s[tid] = x;
    __syncthreads();
    for (int off = 1; off < 256; off <<= 1) {
      int t = (tid >= off) ? s[tid - off] : 0;
      __syncthreads();
      s[tid] += t;
      __syncthreads();
    }
    loc[gid] = s[tid] - x;
    if (tid == 255) bsum[bid - 2816] = s[255];
    return;
  }
  // ---- proj_partial for feat_t: D=384, kchunk=64 (single k-iter) ----
  const int pb = bid;
  const int r0 = (pb & 127) * 64;
  const int ks = pb >> 7;           // 0..5
  const int rg = tid >> 4, cg = tid & 15;
  const int rA = tid & 63, kgA = (tid >> 6) * 16;
  const int kB = tid & 63, cbB = (tid >> 6) * 16;
  const int kbeg = ks * 64;
  const int D = 384;
  float4 pa[4], pb4[4];
  {
    const float* fp = feat + (size_t)(r0 + rA) * D + kbeg + kgA;
    pa[0] = *(const float4*)(fp + 0);  pa[1] = *(const float4*)(fp + 4);
    pa[2] = *(const float4*)(fp + 8);  pa[3] = *(const float4*)(fp + 12);
    const float* wp = W + (size_t)(kbeg + kB) * 64 + cbB;
    pb4[0] = *(const float4*)(wp + 0);  pb4[1] = *(const float4*)(wp + 4);
    pb4[2] = *(const float4*)(wp + 8);  pb4[3] = *(const float4*)(wp + 12);
  }
  float acc[4][4] = {{0,0,0,0},{0,0,0,0},{0,0,0,0},{0,0,0,0}};
#pragma unroll
  for (int i = 0; i < 4; ++i) {
    sA[kgA + 4*i + 0][rA] = pa[i].x;
    sA[kgA + 4*i + 1][rA] = pa[i].y;
    sA[kgA + 4*i + 2][rA] = pa[i].z;
    sA[kgA + 4*i + 3][rA] = pa[i].w;
    *(float4*)&sB[kB][cbB + 4*i] = pb4[i];
  }
  __syncthreads();
#pragma unroll 8
  for (int k = 0; k < 64; ++k) {
    float4 a = *(const float4*)&sA[k][rg * 4];
    float4 b = *(const float4*)&sB[k][cg * 4];
    acc[0][0] += a.x * b.x; acc[0][1] += a.x * b.y; acc[0][2] += a.x * b.z; acc[0][3] += a.x * b.w;
    acc[1][0] += a.y * b.x; acc[1][1] += a.y * b.y; acc[1][2] += a.y * b.z; acc[1][3] += a.y * b.w;
    acc[2][0] += a.z * b.x; acc[2][1] += a.z * b.y; acc[2][2] += a.z * b.z; acc[2][3] += a.z * b.w;
    acc[3][0] += a.w * b.x; acc[3][1] += a.w * b.y; acc[3][2] += a.w * b.z; acc[3][3] += a.w * b.w;
  }
#pragma unroll
  for (int rr = 0; rr < 4; ++rr) {
    float4 o = make_float4(acc[rr][0], acc[rr][1], acc[rr][2], acc[rr][3]);
    *(float4*)(partialT + ((size_t)ks * NI + r0 + rg * 4 + rr) * 64 + cg * 4) = o;
  }
}

// ---------------- fused: proj_reduce_t ∪ scanC ----------------
// bid < 2048: reduce_t (ksplit=6 on partialT). bid >= 2048: scanC (97 blocks).
__global__ __launch_bounds__(256) void fused_reduceT_scanC_kernel(
    const float* __restrict__ partialT, const float* __restrict__ bt,
    float* __restrict__ xn, ushort* __restrict__ hi, ushort* __restrict__ lo,
    const int* __restrict__ loc, const int* __restrict__ bsum,
    int* __restrict__ row_ptr, int* __restrict__ cursor, int n) {
  const int tid = threadIdx.x;
  const int bid = blockIdx.x;
  if (bid >= 2048) {
    int gid = (bid - 2048) * 256 + tid;
    if (gid > n) return;
    int blk = gid >> 8;
    int off = 0;
    for (int b2 = 0; b2 < blk; ++b2) off += bsum[b2];
    if (gid == n) { row_ptr[n] = off; return; }
    int v = off + loc[gid];
    row_ptr[gid] = v;
    cursor[gid] = v;
    return;
  }
  const int row = bid * 4 + (tid >> 6);
  const int col = tid & 63;
  float acc = bt[col];
#pragma unroll
  for (int ks = 0; ks < 6; ++ks)
    acc += partialT[((size_t)ks * NI + row) * 64 + col];
  float ss = warp64_sum(acc * acc);
  float v = acc * (1.0f / sqrtf(ss));
  xn[(size_t)row * 64 + col] = v;
  __hip_bfloat16 hb = __float2bfloat16(v);
  float hf = __bfloat162float(hb);
  __hip_bfloat16 lb = __float2bfloat16(v - hf);
  hi[(size_t)row * 64 + col] = *(ushort*)&hb;
  lo[(size_t)row * 64 + col] = *(ushort*)&lb;
}

// ---------------- fused: sim_tilemax ∪ scan_sim ∪ fill ----------------
// bid < 1024: tilemax (first). 1024 <= bid < 3072: scan_sim (4-deep pipeline).
// bid >= 3072: fill.
__global__ __launch_bounds__(256) void fused_sim_kernel(
    const float* __restrict__ Sv, const float* __restrict__ St,
    const float* __restrict__ iw, int* __restrict__ ocols,
    float* __restrict__ ow, int* __restrict__ ocnt,
    const ushort* __restrict__ hiV, const ushort* __restrict__ loV,
    const ushort* __restrict__ hiT, const ushort* __restrict__ loT,
    float* __restrict__ tmax,
    const int* __restrict__ esrc, const int* __restrict__ edst,
    int* __restrict__ cursor, int* __restrict__ csr, int nedge) {
  __shared__ ushort sH[64][64];
  __shared__ ushort sL[64][64];
  const int tid = threadIdx.x;
  const int bid = blockIdx.x;
  if (bid >= 1024 && bid < 3072) {
    // -------- scan_sim: 4-deep software-pipelined prefetch --------
    const int lane = tid & 63;
    const int row = (bid - 1024) * 4 + (tid >> 6);
    float ea = expf(iw[0]), eb = expf(iw[1]);
    float wA = 0.7f * ea / (ea + eb), wB = 0.7f * eb / (ea + eb);
    int cnt = 0;
    int* oc = ocols + (size_t)row * OCAP;
    float* op = ow + (size_t)row * OCAP;
#pragma unroll 1
    for (int m = 0; m < 2; ++m) {
      const float* S = m ? St : Sv;
      float wgt = m ? wB : wA;
      const float4* rp = (const float4*)(S + (size_t)row * NI);
      float4 buf0 = rp[0 * 64 + lane];
      float4 buf1 = rp[1 * 64 + lane];
      float4 buf2 = rp[2 * 64 + lane];
      float4 buf3 = rp[3 * 64 + lane];
#pragma unroll 1
      for (int it0 = 0; it0 < NI / 256; it0 += 4) {
        float4 n0, n1, n2, n3;
        if (it0 + 4 < NI / 256) {
          n0 = rp[(it0 + 4) * 64 + lane];
          n1 = rp[(it0 + 5) * 64 + lane];
          n2 = rp[(it0 + 6) * 64 + lane];
          n3 = rp[(it0 + 7) * 64 + lane];
        }
#pragma unroll
        for (int k = 0; k < 4; ++k) {
          float4 cur = (k == 0) ? buf0 : (k == 1) ? buf1 : (k == 2) ? buf2 : buf3;
          const int it = it0 + k;
          bool anynz = (cur.x != 0.0f) | (cur.y != 0.0f) | (cur.z != 0.0f) | (cur.w != 0.0f);
          if (__ballot(anynz) != 0ull) {
            int cb = it * 256 + lane * 4;
#pragma unroll
            for (int j = 0; j < 4; ++j) {
              float x = (j == 0) ? cur.x : (j == 1) ? cur.y : (j == 2) ? cur.z : cur.w;
              bool nz = (x != 0.0f);
              unsigned long long mk = __ballot(nz);
              int pre = __popcll(mk & ((1ull << lane) - 1ull));
              if (nz) {
                int p = cnt + pre;
                if (p < OCAP) { oc[p] = cb + j; op[p] = wgt * x; }
              }
              cnt += __popcll(mk);
            }
          }
        }
        buf0 = n0; buf1 = n1; buf2 = n2; buf3 = n3;
      }
    }
    if (lane == 0) ocnt[row] = (cnt < OCAP) ? cnt : OCAP;
    return;
  }
  if (bid >= 3072) {
    // ---------------- fill ----------------
    int e = (bid - 3072) * 256 + tid;
    if (e < nedge) {
      int p = atomicAdd(&cursor[edst[e]], 1);
      csr[p] = esrc[e];
    }
    return;
  }
  // ---------------- sim_tilemax (bids 0..1023) ----------------
  const int t2 = bid;
  const int m = t2 >> 9;
  const int rest = t2 & 511;
  const int seg = rest >> 7;
  const int r_base = (rest & 127) * 64;
  const ushort* hi = m ? hiT : hiV;
  const ushort* lo = m ? loT : loV;
  const int c_base = seg * CSEG;
  const int wave = tid >> 6, lane = tid & 63;
  const int lr = lane & 15, lg = lane >> 4;
  const int my_row = r_base + wave * 16 + lr;
  short8v bh[2], bl[2];
  {
    const ushort* rp = hi + (size_t)my_row * 64 + lg * 8;
    bh[0] = *(const short8v*)(rp);
    bh[1] = *(const short8v*)(rp + 32);
    const ushort* rp2 = lo + (size_t)my_row * 64 + lg * 8;
    bl[0] = *(const short8v*)(rp2);
    bl[1] = *(const short8v*)(rp2 + 32);
  }
  float* tbase = tmax + ((size_t)m * NI + my_row) * NGRP + seg * (CSEG / 16);
  const int sc = tid >> 2, sq = (tid & 3) * 32;
  const int sw = (sc & 7) << 4;  // XOR swizzle (G4)
  for (int c0 = 0; c0 < CSEG; c0 += 64) {
    __syncthreads();
    const char* gh = (const char*)(hi + (size_t)(c_base + c0 + sc) * 64);
    const char* gl2 = (const char*)(lo + (size_t)(c_base + c0 + sc) * 64);
    *(float4*)((char*)&sH[sc][0] + (sq ^ sw)) = *(const float4*)(gh + sq);
    *(float4*)((char*)&sH[sc][0] + ((sq + 16) ^ sw)) = *(const float4*)(gh + sq + 16);
    *(float4*)((char*)&sL[sc][0] + (sq ^ sw)) = *(const float4*)(gl2 + sq);
    *(float4*)((char*)&sL[sc][0] + ((sq + 16) ^ sw)) = *(const float4*)(gl2 + sq + 16);
    __syncthreads();
#pragma unroll
    for (int s = 0; s < 4; ++s) {
      const int ca = s * 16 + lr;
      const int cw = (ca & 7) << 4;
      const int kb0 = (lg * 16) ^ cw;
      const int kb1 = (lg * 16 + 64) ^ cw;
      short8v ah0 = *(const short8v*)((const char*)&sH[ca][0] + kb0);
      short8v ah1 = *(const short8v*)((const char*)&sH[ca][0] + kb1);
      short8v al0 = *(const short8v*)((const char*)&sL[ca][0] + kb0);
      short8v al1 = *(const short8v*)((const char*)&sL[ca][0] + kb1);
      float4v acc = {0.f, 0.f, 0.f, 0.f};
      acc = __builtin_amdgcn_mfma_f32_16x16x32_bf16(ah0, bh[0], acc, 0, 0, 0);
      acc = __builtin_amdgcn_mfma_f32_16x16x32_bf16(ah1, bh[1], acc, 0, 0, 0);
      acc = __builtin_amdgcn_mfma_f32_16x16x32_bf16(ah0, bl[0], acc, 0, 0, 0);
      acc = __builtin_amdgcn_mfma_f32_16x16x32_bf16(ah1, bl[1], acc, 0, 0, 0);
      acc = __builtin_amdgcn_mfma_f32_16x16x32_bf16(al0, bh[0], acc, 0, 0, 0);
      acc = __builtin_amdgcn_mfma_f32_16x16x32_bf16(al1, bh[1], acc, 0, 0, 0);
      float gm = fmaxf(fmaxf(acc[0], acc[1]), fmaxf(acc[2], acc[3]));
      gm = fmaxf(gm, __shfl_xor(gm, 16));
      gm = fmaxf(gm, __shfl_xor(gm, 32));
      if (lg == 0) tbase[(c0 >> 4) + s] = gm;
    }
  }
}

// Pass 2: block per (m,row). Ballot-bisection group select; group-cooperative
// coalesced exact-f32 rescore; ballot-bisection top-10 SET.
__global__ __launch_bounds__(256) void tile_rescore_kernel(
    const float* __restrict__ xn_v, const float* __restrict__ xn_t,
    const float* __restrict__ tmax,
    float* __restrict__ tkvV, int* __restrict__ tkiV,
    float* __restrict__ tkvT, int* __restrict__ tkiT) {
  const int bid = blockIdx.x;
  const int m = bid >> 13;
  const int row = bid & (NI - 1);
  const float* xn = m ? xn_t : xn_v;
  const int tid = threadIdx.x;
  __shared__ int ssel[MAXSEL];
  __shared__ float sval[MAXSEL * 16];
  __shared__ int scol[MAXSEL * 16];
  __shared__ float lv[32];
  __shared__ int lc[32];
  __shared__ int lnum;
  const int grp = tid >> 4, l16 = tid & 15;
  float4 rq = ((const float4*)(xn + (size_t)row * 64))[l16];
  if (tid < 64) {
    const int lane = tid;
    const float4* tmr4 = (const float4*)(tmax + ((size_t)m * NI + row) * NGRP);
    float4 t0 = tmr4[lane];
    float4 t1 = tmr4[64 + lane];
    unsigned int uv[8] = {umap(t0.x), umap(t0.y), umap(t0.z), umap(t0.w),
                          umap(t1.x), umap(t1.y), umap(t1.z), umap(t1.w)};
    unsigned long long blo = 0, bhi = 0x100000000ull;
    unsigned int taub = 0;
    for (int it = 0; it < 34; ++it) {
      unsigned int mid = (unsigned int)((blo + bhi) >> 1);
      int cnt = 0;
#pragma unroll
      for (int j = 0; j < 8; ++j) cnt += __popcll(__ballot(uv[j] >= mid));
      if (cnt >= 12) {
        taub = mid;
        if (cnt <= MAXSEL) break;
        blo = (unsigned long long)mid + 1;
      } else {
        bhi = mid;
      }
      if (blo >= bhi) break;
    }
    unsigned long long bj[8];
    int base[8];
    int tot = 0;
#pragma unroll
    for (int j = 0; j < 8; ++j) {
      bj[j] = __ballot(uv[j] >= taub);
      base[j] = tot;
      tot += __popcll(bj[j]);
    }
    if (lane < MAXSEL) ssel[lane] = -1;
    unsigned long long ltm = (1ull << lane) - 1ull;
#pragma unroll
    for (int j = 0; j < 8; ++j) {
      if (uv[j] >= taub) {
        int pos = base[j] + __popcll(bj[j] & ltm);
        if (pos < MAXSEL) {
          int g = (j < 4) ? (lane * 4 + j) : (256 + lane * 4 + (j - 4));
          ssel[pos] = g;
        }
      }
    }
  }
  __syncthreads();
  for (int it = 0; it < MAXSEL; ++it) {
    int gsel = ssel[it];
    bool valid = (gsel >= 0);
    int c = valid ? (gsel * 16 + grp) : 0;
    float4 x4 = ((const float4*)(xn + (size_t)c * 64))[l16];
    float s = rq.x * x4.x + rq.y * x4.y + rq.z * x4.z + rq.w * x4.w;
    s += __shfl_xor(s, 1);
    s += __shfl_xor(s, 2);
    s += __shfl_xor(s, 4);
    s += __shfl_xor(s, 8);
    if (l16 == 0) {
      sval[it * 16 + grp] = valid ? s : -3.0e38f;
      scol[it * 16 + grp] = valid ? c : 0x7fffffff;
    }
  }
  __syncthreads();
  if (tid < 64) {
    const int lane = tid;
    float fv[4];
    int fc[4];
    unsigned int uv4[4];
#pragma unroll
    for (int k = 0; k < 4; ++k) {
      fv[k] = sval[lane + 64 * k];
      fc[k] = scol[lane + 64 * k];
      uv4[k] = umap(fv[k]);
    }
    unsigned long long blo = 0, bhi = 0x100000000ull;
    unsigned int taub = 0;
    for (int it = 0; it < 34; ++it) {
      unsigned int mid = (unsigned int)((blo + bhi) >> 1);
      int cnt = 0;
#pragma unroll
      for (int k = 0; k < 4; ++k) cnt += __popcll(__ballot(uv4[k] >= mid));
      if (cnt >= TOPK) {
        taub = mid;
        if (cnt == TOPK) break;
        blo = (unsigned long long)mid + 1;
      } else {
        bhi = mid;
      }
      if (blo >= bhi) break;
    }
    unsigned long long bk[4];
    int base[4];
    int tot = 0;
#pragma unroll
    for (int k = 0; k < 4; ++k) {
      bk[k] = __ballot(uv4[k] >= taub);
      base[k] = tot;
      tot += __popcll(bk[k]);
    }
    float* tv = m ? tkvT : tkvV;
    int* ti = m ? tkiT : tkiV;
    unsigned long long ltm = (1ull << lane) - 1ull;
    if (tot == TOPK) {
#pragma unroll
      for (int k = 0; k < 4; ++k) {
        if (uv4[k] >= taub) {
          int pos = base[k] + __popcll(bk[k] & ltm);
          tv[(size_t)row * TOPK + pos] = fv[k];
          ti[(size_t)row * TOPK + pos] = fc[k];
        }
      }
    } else {
#pragma unroll
      for (int k = 0; k < 4; ++k) {
        if (uv4[k] >= taub) {
          int pos = base[k] + __popcll(bk[k] & ltm);
          if (pos < 32) { lv[pos] = fv[k]; lc[pos] = fc[k]; }
        }
      }
      if (lane == 0) lnum = (tot < 32) ? tot : 32;
      if (lane == 0) {
        int n = lnum;
        unsigned int used = 0;
        for (int q = 0; q < TOPK; ++q) {
          float bv = -3.0e38f;
          int bc = 0x7fffffff, bi = -1;
          for (int i2 = 0; i2 < n; ++i2) {
            if (used & (1u << i2)) continue;
            if (lv[i2] > bv || (lv[i2] == bv && lc[i2] < bc)) {
              bv = lv[i2]; bc = lc[i2]; bi = i2;
            }
          }
          used |= (1u << bi);
          tv[(size_t)row * TOPK + q] = bv;
          ti[(size_t)row * TOPK + q] = bc;
        }
      }
    }
  }
}

// dis[r]: d = w0*sum(topk_v)+w1*sum(topk_t)
__global__ void dis_kernel(const float* __restrict__ tkv_v, const float* __restrict__ tkv_t,
                           const float* __restrict__ iw, float* __restrict__ dis) {
  int r = blockIdx.x * blockDim.x + threadIdx.x;
  if (r >= NI) return;
  float ea = expf(iw[0]), eb = expf(iw[1]);
  float w0 = ea / (ea + eb), w1 = eb / (ea + eb);
  float s0 = 0.f, s1 = 0.f;
  for (int j = 0; j < TOPK; ++j) { s0 += tkv_v[r * TOPK + j]; s1 += tkv_t[r * TOPK + j]; }
  float d = w0 * s0 + w1 * s1;
  dis[r] = (d > 0.0f) ? (1.0f / sqrtf(d)) : 0.0f;
}

// ---------------- fused: item_emb ∪ segsum(layer1) ----------------
// bid < 2048: item_emb. bid >= 2048: layer-1 segsum (6144 blocks).
__global__ __launch_bounds__(256) void fused_item_segsum_kernel(
    const float* __restrict__ Gi,
    const float* __restrict__ tkv_v, const int* __restrict__ tki_v,
    const float* __restrict__ tkv_t, const int* __restrict__ tki_t,
    const float* __restrict__ dis, const int* __restrict__ ocols,
    const float* __restrict__ ow, const int* __restrict__ ocnt,
    const float* __restrict__ iw, float* __restrict__ nitem,
    const float* __restrict__ Gu, const int* __restrict__ row_ptr,
    const int* __restrict__ csr, float* __restrict__ e1b) {
  const int tid = threadIdx.x;
  const int d = tid & 63;
  if (blockIdx.x >= 2048) {
    // ---- segsum layer 1 ----
    const int row = (blockIdx.x - 2048) * 4 + (tid >> 6);
    int a = row_ptr[row], bnd = row_ptr[row + 1];
    float acc = 0.0f;
    for (int e = a; e < bnd; ++e) {
      int s = csr[e];
      const float* sp = (s < NU) ? (Gu + (size_t)s * 64) : (Gi + (size_t)(s - NU) * 64);
      acc += sp[d];
    }
    float ss = warp64_sum(acc * acc);
    float nr = sqrtf(ss);
    e1b[(size_t)row * 64 + d] = acc / fmaxf(nr, 1e-12f);
    return;
  }
  // ---- item_emb ----
  const int row = blockIdx.x * 4 + (tid >> 6);
  float ea = expf(iw[0]), eb = expf(iw[1]);
  float w0 = ea / (ea + eb), w1 = eb / (ea + eb);
  float disr = dis[row];
  float acc = 0.0f;
#pragma unroll 1
  for (int m = 0; m < 2; ++m) {
    const float* tv = m ? tkv_t : tkv_v;
    const int* ti = m ? tki_t : tki_v;
    float wm = (m ? w1 : w0) * 0.3f * disr;
    for (int j = 0; j < TOPK; ++j) {
      float val = tv[(size_t)row * TOPK + j];
      int c = ti[(size_t)row * TOPK + j];
      acc += wm * val * dis[c] * Gi[(size_t)c * 64 + d];
    }
  }
  int cn = ocnt[row];
  for (int j = 0; j < cn; ++j) {
    int c = ocols[(size_t)row * OCAP + j];
    float wv = ow[(size_t)row * OCAP + j];
    acc += wv * Gi[(size_t)c * 64 + d];
  }
  float ss = warp64_sum(acc * acc);
  float nr = sqrtf(ss);
  nitem[(size_t)row * 64 + d] = acc / fmaxf(nr, 1e-12f);
}

// layer-2 agg fused with final combine
__global__ __launch_bounds__(256) void segsum_final_kernel(
    const float* __restrict__ e1b, const int* __restrict__ row_ptr,
    const int* __restrict__ csr, const float* __restrict__ Gu,
    const float* __restrict__ Gi, const float* __restrict__ nitem,
    float* __restrict__ outp) {
  const int d = threadIdx.x & 63;
  const int row = blockIdx.x * 4 + (threadIdx.x >> 6);
  const float* inU = e1b;
  const float* inI = e1b + (size_t)NU * 64;
  int a = row_ptr[row], bnd = row_ptr[row + 1];
  float acc = 0.0f;
  for (int e = a; e < bnd; ++e) {
    int s = csr[e];
    const float* sp = (s < NU) ? (inU + (size_t)s * 64) : (inI + (size_t)(s - NU) * 64);
    acc += sp[d];
  }
  float ss = warp64_sum(acc * acc);
  float e2 = acc / fmaxf(sqrtf(ss), 1e-12f);
  float base = (row < NU) ? Gu[(size_t)row * 64 + d] : Gi[(size_t)(row - NU) * 64 + d];
  float v = (base + e1b[(size_t)row * 64 + d] + e2) * (1.0f / 3.0f);
  if (row >= NU) v += nitem[(size_t)(row - NU) * 64 + d];
  outp[(size_t)row * 64 + d] = v;
}

extern "C" void kernel_launch(void* const* d_in, const int* in_sizes, int n_in,
                              void* d_out, int out_size, void* d_ws, size_t ws_size,
                              hipStream_t stream) {
  const float* Gu = (const float*)d_in[0];
  const float* Gi = (const float*)d_in[1];
  const float* feat_v = (const float*)d_in[2];
  const float* feat_t = (const float*)d_in[3];
  const float* W_v = (const float*)d_in[4];
  const float* b_v = (const float*)d_in[5];
  const float* W_t = (const float*)d_in[6];
  const float* b_t = (const float*)d_in[7];
  const float* iw = (const float*)d_in[8];
  const float* Sv = (const float*)d_in[9];
  const float* St = (const float*)d_in[10];
  const int* eidx = (const int*)d_in[11];
  const int twoE = in_sizes[11] / 2;  // 1048576 directed edges
  const int* esrc = eidx;
  const int* edst = eidx + twoE;
  float* outp = (float*)d_out;

  char* w = (char*)d_ws;
  size_t off = 0;
  auto alloc = [&](size_t bytes) -> void* {
    void* p = w + off;
    off = (off + bytes + 255) & ~(size_t)255;
    return p;
  };
  float* xn_v = (float*)alloc((size_t)NI * 64 * 4);
  float* xn_t = (float*)alloc((size_t)NI * 64 * 4);
  ushort* hiV = (ushort*)alloc((size_t)NI * 64 * 2);
  ushort* loV = (ushort*)alloc((size_t)NI * 64 * 2);
  ushort* hiT = (ushort*)alloc((size_t)NI * 64 * 2);
  ushort* loT = (ushort*)alloc((size_t)NI * 64 * 2);
  float* tmax = (float*)alloc((size_t)2 * NI * NGRP * 4);  // 32 MB
  float* tkvV = (float*)alloc((size_t)NI * TOPK * 4);
  int* tkiV = (int*)alloc((size_t)NI * TOPK * 4);
  float* tkvT = (float*)alloc((size_t)NI * TOPK * 4);
  int* tkiT = (int*)alloc((size_t)NI * TOPK * 4);
  float* dis = (float*)alloc((size_t)NI * 4);
  int* ocols = (int*)alloc((size_t)NI * OCAP * 4);
  float* ow = (float*)alloc((size_t)NI * OCAP * 4);
  int* ocnt = (int*)alloc((size_t)NI * 4);
  float* nitem = (float*)alloc((size_t)NI * 64 * 4);
  float* e1b = (float*)alloc((size_t)NTOT * 64 * 4);
  int* deg = (int*)alloc((size_t)NTOT * 4);
  int* row_ptr = (int*)alloc((size_t)(NTOT + 1) * 4);
  int* cursor = (int*)alloc((size_t)NTOT * 4);
  int* csr = (int*)alloc((size_t)twoE * 4);
  int* locb = (int*)alloc((size_t)NTOT * 4);
  int* bsum = (int*)alloc((size_t)(NTOT / 256) * 4);
  if (off > ws_size) return;

  // k-split partial buffers alias tmax (consumed before tilemax writes it):
  // V: 8 ks x NI x 64 = 16.8 MB ; T: 6 ks x NI x 64 = 12.6 MB ; total < 32 MB.
  float* partialV = tmax;
  float* partialT = tmax + (size_t)8 * NI * 64;

  hipMemsetAsync(deg, 0, (size_t)NTOT * 4, stream);

  // proj_v GEMM (first) ∪ edge histogram (backfills)
  fused_proj_hist_kernel<<<1024 + 4096, 256, 0, stream>>>(
      feat_v, W_v, partialV, 4096, 512, edst, deg, twoE);
  // proj_t GEMM (first) ∪ proj_reduce_v ∪ scanA
  fused_projT_reduceV_scanA_kernel<<<768 + 2048 + 96, 256, 0, stream>>>(
      feat_t, W_t, partialT, partialV, b_v, xn_v, hiV, loV, deg, locb, bsum);
  // proj_reduce_t (first) ∪ scanC
  fused_reduceT_scanC_kernel<<<2048 + 97, 256, 0, stream>>>(
      partialT, b_t, xn_t, hiT, loT, locb, bsum, row_ptr, cursor, NTOT);
  // tilemax (first) ∪ scan_sim (4-deep pipeline) ∪ fill
  fused_sim_kernel<<<1024 + 2048 + 4096, 256, 0, stream>>>(
      Sv, St, iw, ocols, ow, ocnt, hiV, loV, hiT, loT, tmax,
      esrc, edst, cursor, csr, twoE);
  tile_rescore_kernel<<<2 * NI, 256, 0, stream>>>(xn_v, xn_t, tmax, tkvV, tkiV,
                                                  tkvT, tkiT);
  dis_kernel<<<(NI + 255) / 256, 256, 0, stream>>>(tkvV, tkvT, iw, dis);
  // item_emb (first) ∪ segsum layer-1
  fused_item_segsum_kernel<<<2048 + NTOT / 4, 256, 0, stream>>>(
      Gi, tkvV, tkiV, tkvT, tkiT, dis, ocols, ow, ocnt, iw, nitem,
      Gu, row_ptr, csr, e1b);
  segsum_final_kernel<<<NTOT / 4, 256, 0, stream>>>(e1b, row_ptr, csr, Gu, Gi, nitem, outp);
}

// Round 21
// 608.714 us; speedup vs baseline: 1.0337x; 1.0337x over previous
//
#include <hip/hip_runtime.h>
#include <hip/hip_bf16.h>

#define NU 16384
#define NI 8192
#define TOPK 10
#define NTOT (NU + NI)   // 24576
#define OCAP 64
#define NSEG2 8
#define CSEG2 (NI / NSEG2) // 1024
#define NGRP 512         // 8192 / 16 : 16-col group maxes
#define MAXSEL 16        // groups rescored per row (>=12 guaranteed coverage)

typedef short short8v __attribute__((ext_vector_type(8)));
typedef float float4v __attribute__((ext_vector_type(4)));

__device__ __forceinline__ float warp64_sum(float v) {
#pragma unroll
  for (int m = 32; m >= 1; m >>= 1) v += __shfl_xor(v, m);
  return v;
}

// monotone f32 -> u32 remap (total order preserved, exact to 1 ulp)
__device__ __forceinline__ unsigned int umap(float f) {
  unsigned int b = __float_as_uint(f);
  return b ^ ((b & 0x80000000u) ? 0xFFFFFFFFu : 0x80000000u);
}

// ---------------- fused: proj_partial(feat_v) ∪ hist ----------------
__global__ __launch_bounds__(256) void fused_proj_hist_kernel(
    const float* __restrict__ feat, const float* __restrict__ W,
    float* __restrict__ partial, int D, int kchunk,
    const int* __restrict__ dst, int* __restrict__ deg, int nedge) {
  __shared__ float sA[64][64];   // [k][r]
  __shared__ float sB[64][68];   // [k][c], padded
  const int tid = threadIdx.x;
  if (blockIdx.x >= 1024) {
    int e = (blockIdx.x - 1024) * 256 + tid;
    if (e < nedge) atomicAdd(&deg[dst[e]], 1);
    return;
  }
  const int pb = blockIdx.x;
  const int r0 = (pb & 127) * 64;
  const int ks = pb >> 7;
  const int rg = tid >> 4, cg = tid & 15;
  const int rA = tid & 63, kgA = (tid >> 6) * 16;
  const int kB = tid & 63, cbB = (tid >> 6) * 16;
  const int kbeg = ks * kchunk, kend = kbeg + kchunk;
  float4 pa[4], pb4[4];
  {
    const float* fp = feat + (size_t)(r0 + rA) * D + kbeg + kgA;
    pa[0] = *(const float4*)(fp + 0);  pa[1] = *(const float4*)(fp + 4);
    pa[2] = *(const float4*)(fp + 8);  pa[3] = *(const float4*)(fp + 12);
    const float* wp = W + (size_t)(kbeg + kB) * 64 + cbB;
    pb4[0] = *(const float4*)(wp + 0);  pb4[1] = *(const float4*)(wp + 4);
    pb4[2] = *(const float4*)(wp + 8);  pb4[3] = *(const float4*)(wp + 12);
  }
  float acc[4][4] = {{0,0,0,0},{0,0,0,0},{0,0,0,0},{0,0,0,0}};
  for (int kc = kbeg; kc < kend; kc += 64) {
#pragma unroll
    for (int i = 0; i < 4; ++i) {
      sA[kgA + 4*i + 0][rA] = pa[i].x;
      sA[kgA + 4*i + 1][rA] = pa[i].y;
      sA[kgA + 4*i + 2][rA] = pa[i].z;
      sA[kgA + 4*i + 3][rA] = pa[i].w;
      *(float4*)&sB[kB][cbB + 4*i] = pb4[i];
    }
    __syncthreads();
    if (kc + 64 < kend) {
      const float* fp = feat + (size_t)(r0 + rA) * D + kc + 64 + kgA;
      pa[0] = *(const float4*)(fp + 0);  pa[1] = *(const float4*)(fp + 4);
      pa[2] = *(const float4*)(fp + 8);  pa[3] = *(const float4*)(fp + 12);
      const float* wp = W + (size_t)(kc + 64 + kB) * 64 + cbB;
      pb4[0] = *(const float4*)(wp + 0);  pb4[1] = *(const float4*)(wp + 4);
      pb4[2] = *(const float4*)(wp + 8);  pb4[3] = *(const float4*)(wp + 12);
    }
#pragma unroll 8
    for (int k = 0; k < 64; ++k) {
      float4 a = *(const float4*)&sA[k][rg * 4];
      float4 b = *(const float4*)&sB[k][cg * 4];
      acc[0][0] += a.x * b.x; acc[0][1] += a.x * b.y; acc[0][2] += a.x * b.z; acc[0][3] += a.x * b.w;
      acc[1][0] += a.y * b.x; acc[1][1] += a.y * b.y; acc[1][2] += a.y * b.z; acc[1][3] += a.y * b.w;
      acc[2][0] += a.z * b.x; acc[2][1] += a.z * b.y; acc[2][2] += a.z * b.z; acc[2][3] += a.z * b.w;
      acc[3][0] += a.w * b.x; acc[3][1] += a.w * b.y; acc[3][2] += a.w * b.z; acc[3][3] += a.w * b.w;
    }
    __syncthreads();
  }
#pragma unroll
  for (int rr = 0; rr < 4; ++rr) {
    float4 o = make_float4(acc[rr][0], acc[rr][1], acc[rr][2], acc[rr][3]);
    *(float4*)(partial + ((size_t)ks * NI + r0 + rg * 4 + rr) * 64 + cg * 4) = o;
  }
}

// ---------------- fused: proj_partial(feat_t) ∪ proj_reduce_v ∪ scanA ------
__global__ __launch_bounds__(256) void fused_projT_reduceV_scanA_kernel(
    const float* __restrict__ feat, const float* __restrict__ W,
    float* __restrict__ partialT,
    const float* __restrict__ partialV, const float* __restrict__ bv,
    float* __restrict__ xn, ushort* __restrict__ hi, ushort* __restrict__ lo,
    const int* __restrict__ deg, int* __restrict__ loc, int* __restrict__ bsum) {
  __shared__ float sA[64][64];
  __shared__ float sB[64][68];
  __shared__ int s[256];
  const int tid = threadIdx.x;
  const int bid = blockIdx.x;
  if (bid >= 768 && bid < 2816) {
    const int row = (bid - 768) * 4 + (tid >> 6);
    const int col = tid & 63;
    float acc = bv[col];
#pragma unroll
    for (int ks = 0; ks < 8; ++ks)
      acc += partialV[((size_t)ks * NI + row) * 64 + col];
    float ss = warp64_sum(acc * acc);
    float v = acc * (1.0f / sqrtf(ss));
    xn[(size_t)row * 64 + col] = v;
    __hip_bfloat16 hb = __float2bfloat16(v);
    float hf = __bfloat162float(hb);
    __hip_bfloat16 lb = __float2bfloat16(v - hf);
    hi[(size_t)row * 64 + col] = *(ushort*)&hb;
    lo[(size_t)row * 64 + col] = *(ushort*)&lb;
    return;
  }
  if (bid >= 2816) {
    int gid = (bid - 2816) * 256 + tid;
    int x = deg[gid];
    s[tid] = x;
    __syncthreads();
    for (int off = 1; off < 256; off <<= 1) {
      int t = (tid >= off) ? s[tid - off] : 0;
      __syncthreads();
      s[tid] += t;
      __syncthreads();
    }
    loc[gid] = s[tid] - x;
    if (tid == 255) bsum[bid - 2816] = s[255];
    return;
  }
  const int pb = bid;
  const int r0 = (pb & 127) * 64;
  const int ks = pb >> 7;           // 0..5
  const int rg = tid >> 4, cg = tid & 15;
  const int rA = tid & 63, kgA = (tid >> 6) * 16;
  const int kB = tid & 63, cbB = (tid >> 6) * 16;
  const int kbeg = ks * 64;
  const int D = 384;
  float4 pa[4], pb4[4];
  {
    const float* fp = feat + (size_t)(r0 + rA) * D + kbeg + kgA;
    pa[0] = *(const float4*)(fp + 0);  pa[1] = *(const float4*)(fp + 4);
    pa[2] = *(const float4*)(fp + 8);  pa[3] = *(const float4*)(fp + 12);
    const float* wp = W + (size_t)(kbeg + kB) * 64 + cbB;
    pb4[0] = *(const float4*)(wp + 0);  pb4[1] = *(const float4*)(wp + 4);
    pb4[2] = *(const float4*)(wp + 8);  pb4[3] = *(const float4*)(wp + 12);
  }
  float acc[4][4] = {{0,0,0,0},{0,0,0,0},{0,0,0,0},{0,0,0,0}};
#pragma unroll
  for (int i = 0; i < 4; ++i) {
    sA[kgA + 4*i + 0][rA] = pa[i].x;
    sA[kgA + 4*i + 1][rA] = pa[i].y;
    sA[kgA + 4*i + 2][rA] = pa[i].z;
    sA[kgA + 4*i + 3][rA] = pa[i].w;
    *(float4*)&sB[kB][cbB + 4*i] = pb4[i];
  }
  __syncthreads();
#pragma unroll 8
  for (int k = 0; k < 64; ++k) {
    float4 a = *(const float4*)&sA[k][rg * 4];
    float4 b = *(const float4*)&sB[k][cg * 4];
    acc[0][0] += a.x * b.x; acc[0][1] += a.x * b.y; acc[0][2] += a.x * b.z; acc[0][3] += a.x * b.w;
    acc[1][0] += a.y * b.x; acc[1][1] += a.y * b.y; acc[1][2] += a.y * b.z; acc[1][3] += a.y * b.w;
    acc[2][0] += a.z * b.x; acc[2][1] += a.z * b.y; acc[2][2] += a.z * b.z; acc[2][3] += a.z * b.w;
    acc[3][0] += a.w * b.x; acc[3][1] += a.w * b.y; acc[3][2] += a.w * b.z; acc[3][3] += a.w * b.w;
  }
#pragma unroll
  for (int rr = 0; rr < 4; ++rr) {
    float4 o = make_float4(acc[rr][0], acc[rr][1], acc[rr][2], acc[rr][3]);
    *(float4*)(partialT + ((size_t)ks * NI + r0 + rg * 4 + rr) * 64 + cg * 4) = o;
  }
}

// ---------------- fused: proj_reduce_t ∪ scanC ----------------
__global__ __launch_bounds__(256) void fused_reduceT_scanC_kernel(
    const float* __restrict__ partialT, const float* __restrict__ bt,
    float* __restrict__ xn, ushort* __restrict__ hi, ushort* __restrict__ lo,
    const int* __restrict__ loc, const int* __restrict__ bsum,
    int* __restrict__ row_ptr, int* __restrict__ cursor, int n) {
  const int tid = threadIdx.x;
  const int bid = blockIdx.x;
  if (bid >= 2048) {
    int gid = (bid - 2048) * 256 + tid;
    if (gid > n) return;
    int blk = gid >> 8;
    int off = 0;
    for (int b2 = 0; b2 < blk; ++b2) off += bsum[b2];
    if (gid == n) { row_ptr[n] = off; return; }
    int v = off + loc[gid];
    row_ptr[gid] = v;
    cursor[gid] = v;
    return;
  }
  const int row = bid * 4 + (tid >> 6);
  const int col = tid & 63;
  float acc = bt[col];
#pragma unroll
  for (int ks = 0; ks < 6; ++ks)
    acc += partialT[((size_t)ks * NI + row) * 64 + col];
  float ss = warp64_sum(acc * acc);
  float v = acc * (1.0f / sqrtf(ss));
  xn[(size_t)row * 64 + col] = v;
  __hip_bfloat16 hb = __float2bfloat16(v);
  float hf = __bfloat162float(hb);
  __hip_bfloat16 lb = __float2bfloat16(v - hf);
  hi[(size_t)row * 64 + col] = *(ushort*)&hb;
  lo[(size_t)row * 64 + col] = *(ushort*)&lb;
}

// ---------------- standalone tilemax: 2048 blocks (full occupancy) --------
// block: m = bid>>10, seg = (bid&1023)>>7 (0..7, 1024-col segs), rows (bid&127)*64.
__global__ __launch_bounds__(256) void sim_tilemax_kernel(
    const ushort* __restrict__ hiV, const ushort* __restrict__ loV,
    const ushort* __restrict__ hiT, const ushort* __restrict__ loT,
    float* __restrict__ tmax) {
  __shared__ ushort sH[64][64];
  __shared__ ushort sL[64][64];
  const int tid = threadIdx.x;
  const int bid = blockIdx.x;
  const int m = bid >> 10;
  const int rest = bid & 1023;
  const int seg = rest >> 7;
  const int r_base = (rest & 127) * 64;
  const ushort* hi = m ? hiT : hiV;
  const ushort* lo = m ? loT : loV;
  const int c_base = seg * CSEG2;
  const int wave = tid >> 6, lane = tid & 63;
  const int lr = lane & 15, lg = lane >> 4;
  const int my_row = r_base + wave * 16 + lr;
  short8v bh[2], bl[2];
  {
    const ushort* rp = hi + (size_t)my_row * 64 + lg * 8;
    bh[0] = *(const short8v*)(rp);
    bh[1] = *(const short8v*)(rp + 32);
    const ushort* rp2 = lo + (size_t)my_row * 64 + lg * 8;
    bl[0] = *(const short8v*)(rp2);
    bl[1] = *(const short8v*)(rp2 + 32);
  }
  float* tbase = tmax + ((size_t)m * NI + my_row) * NGRP + seg * (CSEG2 / 16);
  const int sc = tid >> 2, sq = (tid & 3) * 32;
  const int sw = (sc & 7) << 4;  // XOR swizzle (G4)
  for (int c0 = 0; c0 < CSEG2; c0 += 64) {
    __syncthreads();
    const char* gh = (const char*)(hi + (size_t)(c_base + c0 + sc) * 64);
    const char* gl2 = (const char*)(lo + (size_t)(c_base + c0 + sc) * 64);
    *(float4*)((char*)&sH[sc][0] + (sq ^ sw)) = *(const float4*)(gh + sq);
    *(float4*)((char*)&sH[sc][0] + ((sq + 16) ^ sw)) = *(const float4*)(gh + sq + 16);
    *(float4*)((char*)&sL[sc][0] + (sq ^ sw)) = *(const float4*)(gl2 + sq);
    *(float4*)((char*)&sL[sc][0] + ((sq + 16) ^ sw)) = *(const float4*)(gl2 + sq + 16);
    __syncthreads();
#pragma unroll
    for (int s = 0; s < 4; ++s) {
      const int ca = s * 16 + lr;
      const int cw = (ca & 7) << 4;
      const int kb0 = (lg * 16) ^ cw;
      const int kb1 = (lg * 16 + 64) ^ cw;
      short8v ah0 = *(const short8v*)((const char*)&sH[ca][0] + kb0);
      short8v ah1 = *(const short8v*)((const char*)&sH[ca][0] + kb1);
      short8v al0 = *(const short8v*)((const char*)&sL[ca][0] + kb0);
      short8v al1 = *(const short8v*)((const char*)&sL[ca][0] + kb1);
      float4v acc = {0.f, 0.f, 0.f, 0.f};
      acc = __builtin_amdgcn_mfma_f32_16x16x32_bf16(ah0, bh[0], acc, 0, 0, 0);
      acc = __builtin_amdgcn_mfma_f32_16x16x32_bf16(ah1, bh[1], acc, 0, 0, 0);
      acc = __builtin_amdgcn_mfma_f32_16x16x32_bf16(ah0, bl[0], acc, 0, 0, 0);
      acc = __builtin_amdgcn_mfma_f32_16x16x32_bf16(ah1, bl[1], acc, 0, 0, 0);
      acc = __builtin_amdgcn_mfma_f32_16x16x32_bf16(al0, bh[0], acc, 0, 0, 0);
      acc = __builtin_amdgcn_mfma_f32_16x16x32_bf16(al1, bh[1], acc, 0, 0, 0);
      float gm = fmaxf(fmaxf(acc[0], acc[1]), fmaxf(acc[2], acc[3]));
      gm = fmaxf(gm, __shfl_xor(gm, 16));
      gm = fmaxf(gm, __shfl_xor(gm, 32));
      if (lg == 0) tbase[(c0 >> 4) + s] = gm;
    }
  }
}

// ------- fused: scan_sim ∥ tile_rescore (bid-interleaved 1:8) ∪ fill -------
// bids 0..18431: bid%9==0 -> scan block bid/9 ; else rescore idx bid-bid/9-1.
// bids >= 18432: fill.
__global__ __launch_bounds__(256) void fused_scan_rescore_fill_kernel(
    const float* __restrict__ Sv, const float* __restrict__ St,
    const float* __restrict__ iw, int* __restrict__ ocols,
    float* __restrict__ ow, int* __restrict__ ocnt,
    const float* __restrict__ xn_v, const float* __restrict__ xn_t,
    const float* __restrict__ tmax,
    float* __restrict__ tkvV, int* __restrict__ tkiV,
    float* __restrict__ tkvT, int* __restrict__ tkiT,
    const int* __restrict__ esrc, const int* __restrict__ edst,
    int* __restrict__ cursor, int* __restrict__ csr, int nedge) {
  const int tid = threadIdx.x;
  const int bid0 = blockIdx.x;
  if (bid0 >= 18432) {
    int e = (bid0 - 18432) * 256 + tid;
    if (e < nedge) {
      int p = atomicAdd(&cursor[edst[e]], 1);
      csr[p] = esrc[e];
    }
    return;
  }
  const int sgrp = bid0 / 9;
  if (bid0 % 9 == 0) {
    // -------- scan_sim block sgrp (4-deep pipelined, sparse fast path) -----
    const int lane = tid & 63;
    const int row = sgrp * 4 + (tid >> 6);
    float ea = expf(iw[0]), eb = expf(iw[1]);
    float wA = 0.7f * ea / (ea + eb), wB = 0.7f * eb / (ea + eb);
    int cnt = 0;
    int* oc = ocols + (size_t)row * OCAP;
    float* op = ow + (size_t)row * OCAP;
#pragma unroll 1
    for (int m = 0; m < 2; ++m) {
      const float* S = m ? St : Sv;
      float wgt = m ? wB : wA;
      const float4* rp = (const float4*)(S + (size_t)row * NI);
      float4 buf0 = rp[0 * 64 + lane];
      float4 buf1 = rp[1 * 64 + lane];
      float4 buf2 = rp[2 * 64 + lane];
      float4 buf3 = rp[3 * 64 + lane];
#pragma unroll 1
      for (int it0 = 0; it0 < NI / 256; it0 += 4) {
        float4 n0, n1, n2, n3;
        if (it0 + 4 < NI / 256) {
          n0 = rp[(it0 + 4) * 64 + lane];
          n1 = rp[(it0 + 5) * 64 + lane];
          n2 = rp[(it0 + 6) * 64 + lane];
          n3 = rp[(it0 + 7) * 64 + lane];
        }
#pragma unroll
        for (int k = 0; k < 4; ++k) {
          float4 cur = (k == 0) ? buf0 : (k == 1) ? buf1 : (k == 2) ? buf2 : buf3;
          const int it = it0 + k;
          bool anynz = (cur.x != 0.0f) | (cur.y != 0.0f) | (cur.z != 0.0f) | (cur.w != 0.0f);
          if (__ballot(anynz) != 0ull) {
            int cb = it * 256 + lane * 4;
#pragma unroll
            for (int j = 0; j < 4; ++j) {
              float x = (j == 0) ? cur.x : (j == 1) ? cur.y : (j == 2) ? cur.z : cur.w;
              bool nz = (x != 0.0f);
              unsigned long long mk = __ballot(nz);
              int pre = __popcll(mk & ((1ull << lane) - 1ull));
              if (nz) {
                int p = cnt + pre;
                if (p < OCAP) { oc[p] = cb + j; op[p] = wgt * x; }
              }
              cnt += __popcll(mk);
            }
          }
        }
        buf0 = n0; buf1 = n1; buf2 = n2; buf3 = n3;
      }
    }
    if (lane == 0) ocnt[row] = (cnt < OCAP) ? cnt : OCAP;
    return;
  }
  // ---------------- tile_rescore (interleaved bids) ----------------
  const int bid = bid0 - sgrp - 1;     // 0 .. 2*NI-1
  const int m = bid >> 13;
  const int row = bid & (NI - 1);
  const float* xn = m ? xn_t : xn_v;
  __shared__ int ssel[MAXSEL];
  __shared__ float sval[MAXSEL * 16];
  __shared__ int scol[MAXSEL * 16];
  __shared__ float lv[32];
  __shared__ int lc[32];
  __shared__ int lnum;
  const int grp = tid >> 4, l16 = tid & 15;
  float4 rq = ((const float4*)(xn + (size_t)row * 64))[l16];
  if (tid < 64) {
    const int lane = tid;
    const float4* tmr4 = (const float4*)(tmax + ((size_t)m * NI + row) * NGRP);
    float4 t0 = tmr4[lane];
    float4 t1 = tmr4[64 + lane];
    unsigned int uv[8] = {umap(t0.x), umap(t0.y), umap(t0.z), umap(t0.w),
                          umap(t1.x), umap(t1.y), umap(t1.z), umap(t1.w)};
    unsigned long long blo = 0, bhi = 0x100000000ull;
    unsigned int taub = 0;
    for (int it = 0; it < 34; ++it) {
      unsigned int mid = (unsigned int)((blo + bhi) >> 1);
      int cnt = 0;
#pragma unroll
      for (int j = 0; j < 8; ++j) cnt += __popcll(__ballot(uv[j] >= mid));
      if (cnt >= 12) {
        taub = mid;
        if (cnt <= MAXSEL) break;
        blo = (unsigned long long)mid + 1;
      } else {
        bhi = mid;
      }
      if (blo >= bhi) break;
    }
    unsigned long long bj[8];
    int base[8];
    int tot = 0;
#pragma unroll
    for (int j = 0; j < 8; ++j) {
      bj[j] = __ballot(uv[j] >= taub);
      base[j] = tot;
      tot += __popcll(bj[j]);
    }
    if (lane < MAXSEL) ssel[lane] = -1;
    unsigned long long ltm = (1ull << lane) - 1ull;
#pragma unroll
    for (int j = 0; j < 8; ++j) {
      if (uv[j] >= taub) {
        int pos = base[j] + __popcll(bj[j] & ltm);
        if (pos < MAXSEL) {
          int g = (j < 4) ? (lane * 4 + j) : (256 + lane * 4 + (j - 4));
          ssel[pos] = g;
        }
      }
    }
  }
  __syncthreads();
  for (int it = 0; it < MAXSEL; ++it) {
    int gsel = ssel[it];
    bool valid = (gsel >= 0);
    int c = valid ? (gsel * 16 + grp) : 0;
    float4 x4 = ((const float4*)(xn + (size_t)c * 64))[l16];
    float s = rq.x * x4.x + rq.y * x4.y + rq.z * x4.z + rq.w * x4.w;
    s += __shfl_xor(s, 1);
    s += __shfl_xor(s, 2);
    s += __shfl_xor(s, 4);
    s += __shfl_xor(s, 8);
    if (l16 == 0) {
      sval[it * 16 + grp] = valid ? s : -3.0e38f;
      scol[it * 16 + grp] = valid ? c : 0x7fffffff;
    }
  }
  __syncthreads();
  if (tid < 64) {
    const int lane = tid;
    float fv[4];
    int fc[4];
    unsigned int uv4[4];
#pragma unroll
    for (int k = 0; k < 4; ++k) {
      fv[k] = sval[lane + 64 * k];
      fc[k] = scol[lane + 64 * k];
      uv4[k] = umap(fv[k]);
    }
    unsigned long long blo = 0, bhi = 0x100000000ull;
    unsigned int taub = 0;
    for (int it = 0; it < 34; ++it) {
      unsigned int mid = (unsigned int)((blo + bhi) >> 1);
      int cnt = 0;
#pragma unroll
      for (int k = 0; k < 4; ++k) cnt += __popcll(__ballot(uv4[k] >= mid));
      if (cnt >= TOPK) {
        taub = mid;
        if (cnt == TOPK) break;
        blo = (unsigned long long)mid + 1;
      } else {
        bhi = mid;
      }
      if (blo >= bhi) break;
    }
    unsigned long long bk[4];
    int base[4];
    int tot = 0;
#pragma unroll
    for (int k = 0; k < 4; ++k) {
      bk[k] = __ballot(uv4[k] >= taub);
      base[k] = tot;
      tot += __popcll(bk[k]);
    }
    float* tv = m ? tkvT : tkvV;
    int* ti = m ? tkiT : tkiV;
    unsigned long long ltm = (1ull << lane) - 1ull;
    if (tot == TOPK) {
#pragma unroll
      for (int k = 0; k < 4; ++k) {
        if (uv4[k] >= taub) {
          int pos = base[k] + __popcll(bk[k] & ltm);
          tv[(size_t)row * TOPK + pos] = fv[k];
          ti[(size_t)row * TOPK + pos] = fc[k];
        }
      }
    } else {
#pragma unroll
      for (int k = 0; k < 4; ++k) {
        if (uv4[k] >= taub) {
          int pos = base[k] + __popcll(bk[k] & ltm);
          if (pos < 32) { lv[pos] = fv[k]; lc[pos] = fc[k]; }
        }
      }
      if (lane == 0) lnum = (tot < 32) ? tot : 32;
      if (lane == 0) {
        int n = lnum;
        unsigned int used = 0;
        for (int q = 0; q < TOPK; ++q) {
          float bv = -3.0e38f;
          int bc = 0x7fffffff, bi = -1;
          for (int i2 = 0; i2 < n; ++i2) {
            if (used & (1u << i2)) continue;
            if (lv[i2] > bv || (lv[i2] == bv && lc[i2] < bc)) {
              bv = lv[i2]; bc = lc[i2]; bi = i2;
            }
          }
          used |= (1u << bi);
          tv[(size_t)row * TOPK + q] = bv;
          ti[(size_t)row * TOPK + q] = bc;
        }
      }
    }
  }
}

// dis[r]: d = w0*sum(topk_v)+w1*sum(topk_t)
__global__ void dis_kernel(const float* __restrict__ tkv_v, const float* __restrict__ tkv_t,
                           const float* __restrict__ iw, float* __restrict__ dis) {
  int r = blockIdx.x * blockDim.x + threadIdx.x;
  if (r >= NI) return;
  float ea = expf(iw[0]), eb = expf(iw[1]);
  float w0 = ea / (ea + eb), w1 = eb / (ea + eb);
  float s0 = 0.f, s1 = 0.f;
  for (int j = 0; j < TOPK; ++j) { s0 += tkv_v[r * TOPK + j]; s1 += tkv_t[r * TOPK + j]; }
  float d = w0 * s0 + w1 * s1;
  dis[r] = (d > 0.0f) ? (1.0f / sqrtf(d)) : 0.0f;
}

// ---------------- fused: item_emb ∪ segsum(layer1) ----------------
__global__ __launch_bounds__(256) void fused_item_segsum_kernel(
    const float* __restrict__ Gi,
    const float* __restrict__ tkv_v, const int* __restrict__ tki_v,
    const float* __restrict__ tkv_t, const int* __restrict__ tki_t,
    const float* __restrict__ dis, const int* __restrict__ ocols,
    const float* __restrict__ ow, const int* __restrict__ ocnt,
    const float* __restrict__ iw, float* __restrict__ nitem,
    const float* __restrict__ Gu, const int* __restrict__ row_ptr,
    const int* __restrict__ csr, float* __restrict__ e1b) {
  const int tid = threadIdx.x;
  const int d = tid & 63;
  if (blockIdx.x >= 2048) {
    const int row = (blockIdx.x - 2048) * 4 + (tid >> 6);
    int a = row_ptr[row], bnd = row_ptr[row + 1];
    float acc = 0.0f;
    for (int e = a; e < bnd; ++e) {
      int s = csr[e];
      const float* sp = (s < NU) ? (Gu + (size_t)s * 64) : (Gi + (size_t)(s - NU) * 64);
      acc += sp[d];
    }
    float ss = warp64_sum(acc * acc);
    float nr = sqrtf(ss);
    e1b[(size_t)row * 64 + d] = acc / fmaxf(nr, 1e-12f);
    return;
  }
  const int row = blockIdx.x * 4 + (tid >> 6);
  float ea = expf(iw[0]), eb = expf(iw[1]);
  float w0 = ea / (ea + eb), w1 = eb / (ea + eb);
  float disr = dis[row];
  float acc = 0.0f;
#pragma unroll 1
  for (int m = 0; m < 2; ++m) {
    const float* tv = m ? tkv_t : tkv_v;
    const int* ti = m ? tki_t : tki_v;
    float wm = (m ? w1 : w0) * 0.3f * disr;
    for (int j = 0; j < TOPK; ++j) {
      float val = tv[(size_t)row * TOPK + j];
      int c = ti[(size_t)row * TOPK + j];
      acc += wm * val * dis[c] * Gi[(size_t)c * 64 + d];
    }
  }
  int cn = ocnt[row];
  for (int j = 0; j < cn; ++j) {
    int c = ocols[(size_t)row * OCAP + j];
    float wv = ow[(size_t)row * OCAP + j];
    acc += wv * Gi[(size_t)c * 64 + d];
  }
  float ss = warp64_sum(acc * acc);
  float nr = sqrtf(ss);
  nitem[(size_t)row * 64 + d] = acc / fmaxf(nr, 1e-12f);
}

// layer-2 agg fused with final combine
__global__ __launch_bounds__(256) void segsum_final_kernel(
    const float* __restrict__ e1b, const int* __restrict__ row_ptr,
    const int* __restrict__ csr, const float* __restrict__ Gu,
    const float* __restrict__ Gi, const float* __restrict__ nitem,
    float* __restrict__ outp) {
  const int d = threadIdx.x & 63;
  const int row = blockIdx.x * 4 + (threadIdx.x >> 6);
  const float* inU = e1b;
  const float* inI = e1b + (size_t)NU * 64;
  int a = row_ptr[row], bnd = row_ptr[row + 1];
  float acc = 0.0f;
  for (int e = a; e < bnd; ++e) {
    int s = csr[e];
    const float* sp = (s < NU) ? (inU + (size_t)s * 64) : (inI + (size_t)(s - NU) * 64);
    acc += sp[d];
  }
  float ss = warp64_sum(acc * acc);
  float e2 = acc / fmaxf(sqrtf(ss), 1e-12f);
  float base = (row < NU) ? Gu[(size_t)row * 64 + d] : Gi[(size_t)(row - NU) * 64 + d];
  float v = (base + e1b[(size_t)row * 64 + d] + e2) * (1.0f / 3.0f);
  if (row >= NU) v += nitem[(size_t)(row - NU) * 64 + d];
  outp[(size_t)row * 64 + d] = v;
}

extern "C" void kernel_launch(void* const* d_in, const int* in_sizes, int n_in,
                              void* d_out, int out_size, void* d_ws, size_t ws_size,
                              hipStream_t stream) {
  const float* Gu = (const float*)d_in[0];
  const float* Gi = (const float*)d_in[1];
  const float* feat_v = (const float*)d_in[2];
  const float* feat_t = (const float*)d_in[3];
  const float* W_v = (const float*)d_in[4];
  const float* b_v = (const float*)d_in[5];
  const float* W_t = (const float*)d_in[6];
  const float* b_t = (const float*)d_in[7];
  const float* iw = (const float*)d_in[8];
  const float* Sv = (const float*)d_in[9];
  const float* St = (const float*)d_in[10];
  const int* eidx = (const int*)d_in[11];
  const int twoE = in_sizes[11] / 2;  // 1048576 directed edges
  const int* esrc = eidx;
  const int* edst = eidx + twoE;
  float* outp = (float*)d_out;

  char* w = (char*)d_ws;
  size_t off = 0;
  auto alloc = [&](size_t bytes) -> void* {
    void* p = w + off;
    off = (off + bytes + 255) & ~(size_t)255;
    return p;
  };
  float* xn_v = (float*)alloc((size_t)NI * 64 * 4);
  float* xn_t = (float*)alloc((size_t)NI * 64 * 4);
  ushort* hiV = (ushort*)alloc((size_t)NI * 64 * 2);
  ushort* loV = (ushort*)alloc((size_t)NI * 64 * 2);
  ushort* hiT = (ushort*)alloc((size_t)NI * 64 * 2);
  ushort* loT = (ushort*)alloc((size_t)NI * 64 * 2);
  float* tmax = (float*)alloc((size_t)2 * NI * NGRP * 4);  // 32 MB
  float* tkvV = (float*)alloc((size_t)NI * TOPK * 4);
  int* tkiV = (int*)alloc((size_t)NI * TOPK * 4);
  float* tkvT = (float*)alloc((size_t)NI * TOPK * 4);
  int* tkiT = (int*)alloc((size_t)NI * TOPK * 4);
  float* dis = (float*)alloc((size_t)NI * 4);
  int* ocols = (int*)alloc((size_t)NI * OCAP * 4);
  float* ow = (float*)alloc((size_t)NI * OCAP * 4);
  int* ocnt = (int*)alloc((size_t)NI * 4);
  float* nitem = (float*)alloc((size_t)NI * 64 * 4);
  float* e1b = (float*)alloc((size_t)NTOT * 64 * 4);
  int* deg = (int*)alloc((size_t)NTOT * 4);
  int* row_ptr = (int*)alloc((size_t)(NTOT + 1) * 4);
  int* cursor = (int*)alloc((size_t)NTOT * 4);
  int* csr = (int*)alloc((size_t)twoE * 4);
  int* locb = (int*)alloc((size_t)NTOT * 4);
  int* bsum = (int*)alloc((size_t)(NTOT / 256) * 4);
  if (off > ws_size) return;

  // k-split partial buffers alias tmax (consumed before tilemax writes it)
  float* partialV = tmax;
  float* partialT = tmax + (size_t)8 * NI * 64;

  hipMemsetAsync(deg, 0, (size_t)NTOT * 4, stream);

  // proj_v GEMM (first) ∪ edge histogram (backfills)
  fused_proj_hist_kernel<<<1024 + 4096, 256, 0, stream>>>(
      feat_v, W_v, partialV, 4096, 512, edst, deg, twoE);
  // proj_t GEMM (first) ∪ proj_reduce_v ∪ scanA
  fused_projT_reduceV_scanA_kernel<<<768 + 2048 + 96, 256, 0, stream>>>(
      feat_t, W_t, partialT, partialV, b_v, xn_v, hiV, loV, deg, locb, bsum);
  // proj_reduce_t (first) ∪ scanC
  fused_reduceT_scanC_kernel<<<2048 + 97, 256, 0, stream>>>(
      partialT, b_t, xn_t, hiT, loT, locb, bsum, row_ptr, cursor, NTOT);
  // tilemax standalone at full occupancy (2048 blocks)
  sim_tilemax_kernel<<<2048, 256, 0, stream>>>(hiV, loV, hiT, loT, tmax);
  // scan_sim ∥ rescore (1:8 bid interleave) ∪ fill
  fused_scan_rescore_fill_kernel<<<18432 + 4096, 256, 0, stream>>>(
      Sv, St, iw, ocols, ow, ocnt, xn_v, xn_t, tmax, tkvV, tkiV, tkvT, tkiT,
      esrc, edst, cursor, csr, twoE);
  dis_kernel<<<(NI + 255) / 256, 256, 0, stream>>>(tkvV, tkvT, iw, dis);
  // item_emb (first) ∪ segsum layer-1
  fused_item_segsum_kernel<<<2048 + NTOT / 4, 256, 0, stream>>>(
      Gi, tkvV, tkiV, tkvT, tkiT, dis, ocols, ow, ocnt, iw, nitem,
      Gu, row_ptr, csr, e1b);
  segsum_final_kernel<<<NTOT / 4, 256, 0, stream>>>(e1b, row_ptr, csr, Gu, Gi, nitem, outp);
}

// Round 23
// 607.879 us; speedup vs baseline: 1.0352x; 1.0014x over previous
//
#include <hip/hip_runtime.h>
#include <hip/hip_bf16.h>

#define NU 16384
#define NI 8192
#define TOPK 10
#define NTOT (NU + NI)   // 24576
#define OCAP 64
#define NSEG2 8
#define CSEG2 (NI / NSEG2) // 1024
#define NGRP 512         // 8192 / 16 : 16-col group maxes
#define MAXSEL 16        // groups rescored per row (>=12 guaranteed coverage)

typedef short short8v __attribute__((ext_vector_type(8)));
typedef float float4v __attribute__((ext_vector_type(4)));

__device__ __forceinline__ float warp64_sum(float v) {
#pragma unroll
  for (int m = 32; m >= 1; m >>= 1) v += __shfl_xor(v, m);
  return v;
}

// monotone f32 -> u32 remap (total order preserved, exact to 1 ulp)
__device__ __forceinline__ unsigned int umap(float f) {
  unsigned int b = __float_as_uint(f);
  return b ^ ((b & 0x80000000u) ? 0xFFFFFFFFu : 0x80000000u);
}

// ---------------- fused: proj_partial(feat_v) ∪ hist ----------------
__global__ __launch_bounds__(256) void fused_proj_hist_kernel(
    const float* __restrict__ feat, const float* __restrict__ W,
    float* __restrict__ partial, int D, int kchunk,
    const int* __restrict__ dst, int* __restrict__ deg, int nedge) {
  __shared__ float sA[64][64];   // [k][r]
  __shared__ float sB[64][68];   // [k][c], padded
  const int tid = threadIdx.x;
  if (blockIdx.x >= 1024) {
    int e = (blockIdx.x - 1024) * 256 + tid;
    if (e < nedge) atomicAdd(&deg[dst[e]], 1);
    return;
  }
  const int pb = blockIdx.x;
  const int r0 = (pb & 127) * 64;
  const int ks = pb >> 7;
  const int rg = tid >> 4, cg = tid & 15;
  const int rA = tid & 63, kgA = (tid >> 6) * 16;
  const int kB = tid & 63, cbB = (tid >> 6) * 16;
  const int kbeg = ks * kchunk, kend = kbeg + kchunk;
  float4 pa[4], pb4[4];
  {
    const float* fp = feat + (size_t)(r0 + rA) * D + kbeg + kgA;
    pa[0] = *(const float4*)(fp + 0);  pa[1] = *(const float4*)(fp + 4);
    pa[2] = *(const float4*)(fp + 8);  pa[3] = *(const float4*)(fp + 12);
    const float* wp = W + (size_t)(kbeg + kB) * 64 + cbB;
    pb4[0] = *(const float4*)(wp + 0);  pb4[1] = *(const float4*)(wp + 4);
    pb4[2] = *(const float4*)(wp + 8);  pb4[3] = *(const float4*)(wp + 12);
  }
  float acc[4][4] = {{0,0,0,0},{0,0,0,0},{0,0,0,0},{0,0,0,0}};
  for (int kc = kbeg; kc < kend; kc += 64) {
#pragma unroll
    for (int i = 0; i < 4; ++i) {
      sA[kgA + 4*i + 0][rA] = pa[i].x;
      sA[kgA + 4*i + 1][rA] = pa[i].y;
      sA[kgA + 4*i + 2][rA] = pa[i].z;
      sA[kgA + 4*i + 3][rA] = pa[i].w;
      *(float4*)&sB[kB][cbB + 4*i] = pb4[i];
    }
    __syncthreads();
    if (kc + 64 < kend) {
      const float* fp = feat + (size_t)(r0 + rA) * D + kc + 64 + kgA;
      pa[0] = *(const float4*)(fp + 0);  pa[1] = *(const float4*)(fp + 4);
      pa[2] = *(const float4*)(fp + 8);  pa[3] = *(const float4*)(fp + 12);
      const float* wp = W + (size_t)(kc + 64 + kB) * 64 + cbB;
      pb4[0] = *(const float4*)(wp + 0);  pb4[1] = *(const float4*)(wp + 4);
      pb4[2] = *(const float4*)(wp + 8);  pb4[3] = *(const float4*)(wp + 12);
    }
#pragma unroll 8
    for (int k = 0; k < 64; ++k) {
      float4 a = *(const float4*)&sA[k][rg * 4];
      float4 b = *(const float4*)&sB[k][cg * 4];
      acc[0][0] += a.x * b.x; acc[0][1] += a.x * b.y; acc[0][2] += a.x * b.z; acc[0][3] += a.x * b.w;
      acc[1][0] += a.y * b.x; acc[1][1] += a.y * b.y; acc[1][2] += a.y * b.z; acc[1][3] += a.y * b.w;
      acc[2][0] += a.z * b.x; acc[2][1] += a.z * b.y; acc[2][2] += a.z * b.z; acc[2][3] += a.z * b.w;
      acc[3][0] += a.w * b.x; acc[3][1] += a.w * b.y; acc[3][2] += a.w * b.z; acc[3][3] += a.w * b.w;
    }
    __syncthreads();
  }
#pragma unroll
  for (int rr = 0; rr < 4; ++rr) {
    float4 o = make_float4(acc[rr][0], acc[rr][1], acc[rr][2], acc[rr][3]);
    *(float4*)(partial + ((size_t)ks * NI + r0 + rg * 4 + rr) * 64 + cg * 4) = o;
  }
}

// ---------------- fused: proj_partial(feat_t) ∪ proj_reduce_v ∪ scanA ------
__global__ __launch_bounds__(256) void fused_projT_reduceV_scanA_kernel(
    const float* __restrict__ feat, const float* __restrict__ W,
    float* __restrict__ partialT,
    const float* __restrict__ partialV, const float* __restrict__ bv,
    float* __restrict__ xn, ushort* __restrict__ hi, ushort* __restrict__ lo,
    const int* __restrict__ deg, int* __restrict__ loc, int* __restrict__ bsum) {
  __shared__ float sA[64][64];
  __shared__ float sB[64][68];
  __shared__ int s[256];
  const int tid = threadIdx.x;
  const int bid = blockIdx.x;
  if (bid >= 768 && bid < 2816) {
    const int row = (bid - 768) * 4 + (tid >> 6);
    const int col = tid & 63;
    float acc = bv[col];
#pragma unroll
    for (int ks = 0; ks < 8; ++ks)
      acc += partialV[((size_t)ks * NI + row) * 64 + col];
    float ss = warp64_sum(acc * acc);
    float v = acc * (1.0f / sqrtf(ss));
    xn[(size_t)row * 64 + col] = v;
    __hip_bfloat16 hb = __float2bfloat16(v);
    float hf = __bfloat162float(hb);
    __hip_bfloat16 lb = __float2bfloat16(v - hf);
    hi[(size_t)row * 64 + col] = *(ushort*)&hb;
    lo[(size_t)row * 64 + col] = *(ushort*)&lb;
    return;
  }
  if (bid >= 2816) {
    int gid = (bid - 2816) * 256 + tid;
    int x = deg[gid];
    s[tid] = x;
    __syncthreads();
    for (int off = 1; off < 256; off <<= 1) {
      int t = (tid >= off) ? s[tid - off] : 0;
      __syncthreads();
      s[tid] += t;
      __syncthreads();
    }
    loc[gid] = s[tid] - x;
    if (tid == 255) bsum[bid - 2816] = s[255];
    return;
  }
  const int pb = bid;
  const int r0 = (pb & 127) * 64;
  const int ks = pb >> 7;           // 0..5
  const int rg = tid >> 4, cg = tid & 15;
  const int rA = tid & 63, kgA = (tid >> 6) * 16;
  const int kB = tid & 63, cbB = (tid >> 6) * 16;
  const int kbeg = ks * 64;
  const int D = 384;
  float4 pa[4], pb4[4];
  {
    const float* fp = feat + (size_t)(r0 + rA) * D + kbeg + kgA;
    pa[0] = *(const float4*)(fp + 0);  pa[1] = *(const float4*)(fp + 4);
    pa[2] = *(const float4*)(fp + 8);  pa[3] = *(const float4*)(fp + 12);
    const float* wp = W + (size_t)(kbeg + kB) * 64 + cbB;
    pb4[0] = *(const float4*)(wp + 0);  pb4[1] = *(const float4*)(wp + 4);
    pb4[2] = *(const float4*)(wp + 8);  pb4[3] = *(const float4*)(wp + 12);
  }
  float acc[4][4] = {{0,0,0,0},{0,0,0,0},{0,0,0,0},{0,0,0,0}};
#pragma unroll
  for (int i = 0; i < 4; ++i) {
    sA[kgA + 4*i + 0][rA] = pa[i].x;
    sA[kgA + 4*i + 1][rA] = pa[i].y;
    sA[kgA + 4*i + 2][rA] = pa[i].z;
    sA[kgA + 4*i + 3][rA] = pa[i].w;
    *(float4*)&sB[kB][cbB + 4*i] = pb4[i];
  }
  __syncthreads();
#pragma unroll 8
  for (int k = 0; k < 64; ++k) {
    float4 a = *(const float4*)&sA[k][rg * 4];
    float4 b = *(const float4*)&sB[k][cg * 4];
    acc[0][0] += a.x * b.x; acc[0][1] += a.x * b.y; acc[0][2] += a.x * b.z; acc[0][3] += a.x * b.w;
    acc[1][0] += a.y * b.x; acc[1][1] += a.y * b.y; acc[1][2] += a.y * b.z; acc[1][3] += a.y * b.w;
    acc[2][0] += a.z * b.x; acc[2][1] += a.z * b.y; acc[2][2] += a.z * b.z; acc[2][3] += a.z * b.w;
    acc[3][0] += a.w * b.x; acc[3][1] += a.w * b.y; acc[3][2] += a.w * b.z; acc[3][3] += a.w * b.w;
  }
#pragma unroll
  for (int rr = 0; rr < 4; ++rr) {
    float4 o = make_float4(acc[rr][0], acc[rr][1], acc[rr][2], acc[rr][3]);
    *(float4*)(partialT + ((size_t)ks * NI + r0 + rg * 4 + rr) * 64 + cg * 4) = o;
  }
}

// ---------------- fused: proj_reduce_t ∪ scanC ----------------
__global__ __launch_bounds__(256) void fused_reduceT_scanC_kernel(
    const float* __restrict__ partialT, const float* __restrict__ bt,
    float* __restrict__ xn, ushort* __restrict__ hi, ushort* __restrict__ lo,
    const int* __restrict__ loc, const int* __restrict__ bsum,
    int* __restrict__ row_ptr, int* __restrict__ cursor, int n) {
  const int tid = threadIdx.x;
  const int bid = blockIdx.x;
  if (bid >= 2048) {
    int gid = (bid - 2048) * 256 + tid;
    if (gid > n) return;
    int blk = gid >> 8;
    int off = 0;
    for (int b2 = 0; b2 < blk; ++b2) off += bsum[b2];
    if (gid == n) { row_ptr[n] = off; return; }
    int v = off + loc[gid];
    row_ptr[gid] = v;
    cursor[gid] = v;
    return;
  }
  const int row = bid * 4 + (tid >> 6);
  const int col = tid & 63;
  float acc = bt[col];
#pragma unroll
  for (int ks = 0; ks < 6; ++ks)
    acc += partialT[((size_t)ks * NI + row) * 64 + col];
  float ss = warp64_sum(acc * acc);
  float v = acc * (1.0f / sqrtf(ss));
  xn[(size_t)row * 64 + col] = v;
  __hip_bfloat16 hb = __float2bfloat16(v);
  float hf = __bfloat162float(hb);
  __hip_bfloat16 lb = __float2bfloat16(v - hf);
  hi[(size_t)row * 64 + col] = *(ushort*)&hb;
  lo[(size_t)row * 64 + col] = *(ushort*)&lb;
}

// ---------------- standalone tilemax: 2048 blocks (full occupancy) --------
// block: m = bid>>10, seg = (bid&1023)>>7 (0..7, 1024-col segs), rows (bid&127)*64.
__global__ __launch_bounds__(256) void sim_tilemax_kernel(
    const ushort* __restrict__ hiV, const ushort* __restrict__ loV,
    const ushort* __restrict__ hiT, const ushort* __restrict__ loT,
    float* __restrict__ tmax) {
  __shared__ ushort sH[64][64];
  __shared__ ushort sL[64][64];
  const int tid = threadIdx.x;
  const int bid = blockIdx.x;
  const int m = bid >> 10;
  const int rest = bid & 1023;
  const int seg = rest >> 7;
  const int r_base = (rest & 127) * 64;
  const ushort* hi = m ? hiT : hiV;
  const ushort* lo = m ? loT : loV;
  const int c_base = seg * CSEG2;
  const int wave = tid >> 6, lane = tid & 63;
  const int lr = lane & 15, lg = lane >> 4;
  const int my_row = r_base + wave * 16 + lr;
  short8v bh[2], bl[2];
  {
    const ushort* rp = hi + (size_t)my_row * 64 + lg * 8;
    bh[0] = *(const short8v*)(rp);
    bh[1] = *(const short8v*)(rp + 32);
    const ushort* rp2 = lo + (size_t)my_row * 64 + lg * 8;
    bl[0] = *(const short8v*)(rp2);
    bl[1] = *(const short8v*)(rp2 + 32);
  }
  float* tbase = tmax + ((size_t)m * NI + my_row) * NGRP + seg * (CSEG2 / 16);
  const int sc = tid >> 2, sq = (tid & 3) * 32;
  const int sw = (sc & 7) << 4;  // XOR swizzle (G4)
  for (int c0 = 0; c0 < CSEG2; c0 += 64) {
    __syncthreads();
    const char* gh = (const char*)(hi + (size_t)(c_base + c0 + sc) * 64);
    const char* gl2 = (const char*)(lo + (size_t)(c_base + c0 + sc) * 64);
    *(float4*)((char*)&sH[sc][0] + (sq ^ sw)) = *(const float4*)(gh + sq);
    *(float4*)((char*)&sH[sc][0] + ((sq + 16) ^ sw)) = *(const float4*)(gh + sq + 16);
    *(float4*)((char*)&sL[sc][0] + (sq ^ sw)) = *(const float4*)(gl2 + sq);
    *(float4*)((char*)&sL[sc][0] + ((sq + 16) ^ sw)) = *(const float4*)(gl2 + sq + 16);
    __syncthreads();
#pragma unroll
    for (int s = 0; s < 4; ++s) {
      const int ca = s * 16 + lr;
      const int cw = (ca & 7) << 4;
      const int kb0 = (lg * 16) ^ cw;
      const int kb1 = (lg * 16 + 64) ^ cw;
      short8v ah0 = *(const short8v*)((const char*)&sH[ca][0] + kb0);
      short8v ah1 = *(const short8v*)((const char*)&sH[ca][0] + kb1);
      short8v al0 = *(const short8v*)((const char*)&sL[ca][0] + kb0);
      short8v al1 = *(const short8v*)((const char*)&sL[ca][0] + kb1);
      float4v acc = {0.f, 0.f, 0.f, 0.f};
      acc = __builtin_amdgcn_mfma_f32_16x16x32_bf16(ah0, bh[0], acc, 0, 0, 0);
      acc = __builtin_amdgcn_mfma_f32_16x16x32_bf16(ah1, bh[1], acc, 0, 0, 0);
      acc = __builtin_amdgcn_mfma_f32_16x16x32_bf16(ah0, bl[0], acc, 0, 0, 0);
      acc = __builtin_amdgcn_mfma_f32_16x16x32_bf16(ah1, bl[1], acc, 0, 0, 0);
      acc = __builtin_amdgcn_mfma_f32_16x16x32_bf16(al0, bh[0], acc, 0, 0, 0);
      acc = __builtin_amdgcn_mfma_f32_16x16x32_bf16(al1, bh[1], acc, 0, 0, 0);
      float gm = fmaxf(fmaxf(acc[0], acc[1]), fmaxf(acc[2], acc[3]));
      gm = fmaxf(gm, __shfl_xor(gm, 16));
      gm = fmaxf(gm, __shfl_xor(gm, 32));
      if (lg == 0) tbase[(c0 >> 4) + s] = gm;
    }
  }
}

// ------- fused: scan_sim ∥ tile_rescore (bid-interleaved 1:8) ∪ fill -------
// bids 0..18431: bid%9==0 -> scan block bid/9 ; else rescore idx bid-bid/9-1.
// bids >= 18432: fill.
__global__ __launch_bounds__(256) void fused_scan_rescore_fill_kernel(
    const float* __restrict__ Sv, const float* __restrict__ St,
    const float* __restrict__ iw, int* __restrict__ ocols,
    float* __restrict__ ow, int* __restrict__ ocnt,
    const float* __restrict__ xn_v, const float* __restrict__ xn_t,
    const float* __restrict__ tmax,
    float* __restrict__ tkvV, int* __restrict__ tkiV,
    float* __restrict__ tkvT, int* __restrict__ tkiT,
    const int* __restrict__ esrc, const int* __restrict__ edst,
    int* __restrict__ cursor, int* __restrict__ csr, int nedge) {
  const int tid = threadIdx.x;
  const int bid0 = blockIdx.x;
  if (bid0 >= 18432) {
    int e = (bid0 - 18432) * 256 + tid;
    if (e < nedge) {
      int p = atomicAdd(&cursor[edst[e]], 1);
      csr[p] = esrc[e];
    }
    return;
  }
  const int sgrp = bid0 / 9;
  if (bid0 % 9 == 0) {
    // -------- scan_sim block sgrp (4-deep pipelined, sparse fast path) -----
    const int lane = tid & 63;
    const int row = sgrp * 4 + (tid >> 6);
    float ea = expf(iw[0]), eb = expf(iw[1]);
    float wA = 0.7f * ea / (ea + eb), wB = 0.7f * eb / (ea + eb);
    int cnt = 0;
    int* oc = ocols + (size_t)row * OCAP;
    float* op = ow + (size_t)row * OCAP;
#pragma unroll 1
    for (int m = 0; m < 2; ++m) {
      const float* S = m ? St : Sv;
      float wgt = m ? wB : wA;
      const float4* rp = (const float4*)(S + (size_t)row * NI);
      float4 buf0 = rp[0 * 64 + lane];
      float4 buf1 = rp[1 * 64 + lane];
      float4 buf2 = rp[2 * 64 + lane];
      float4 buf3 = rp[3 * 64 + lane];
#pragma unroll 1
      for (int it0 = 0; it0 < NI / 256; it0 += 4) {
        float4 n0, n1, n2, n3;
        if (it0 + 4 < NI / 256) {
          n0 = rp[(it0 + 4) * 64 + lane];
          n1 = rp[(it0 + 5) * 64 + lane];
          n2 = rp[(it0 + 6) * 64 + lane];
          n3 = rp[(it0 + 7) * 64 + lane];
        }
#pragma unroll
        for (int k = 0; k < 4; ++k) {
          float4 cur = (k == 0) ? buf0 : (k == 1) ? buf1 : (k == 2) ? buf2 : buf3;
          const int it = it0 + k;
          bool anynz = (cur.x != 0.0f) | (cur.y != 0.0f) | (cur.z != 0.0f) | (cur.w != 0.0f);
          if (__ballot(anynz) != 0ull) {
            int cb = it * 256 + lane * 4;
#pragma unroll
            for (int j = 0; j < 4; ++j) {
              float x = (j == 0) ? cur.x : (j == 1) ? cur.y : (j == 2) ? cur.z : cur.w;
              bool nz = (x != 0.0f);
              unsigned long long mk = __ballot(nz);
              int pre = __popcll(mk & ((1ull << lane) - 1ull));
              if (nz) {
                int p = cnt + pre;
                if (p < OCAP) { oc[p] = cb + j; op[p] = wgt * x; }
              }
              cnt += __popcll(mk);
            }
          }
        }
        buf0 = n0; buf1 = n1; buf2 = n2; buf3 = n3;
      }
    }
    if (lane == 0) ocnt[row] = (cnt < OCAP) ? cnt : OCAP;
    return;
  }
  // ---------------- tile_rescore (interleaved bids) ----------------
  const int bid = bid0 - sgrp - 1;     // 0 .. 2*NI-1
  const int m = bid >> 13;
  const int row = bid & (NI - 1);
  const float* xn = m ? xn_t : xn_v;
  __shared__ int ssel[MAXSEL];
  __shared__ float sval[MAXSEL * 16];
  __shared__ int scol[MAXSEL * 16];
  __shared__ float lv[32];
  __shared__ int lc[32];
  __shared__ int lnum;
  const int grp = tid >> 4, l16 = tid & 15;
  float4 rq = ((const float4*)(xn + (size_t)row * 64))[l16];
  if (tid < 64) {
    const int lane = tid;
    const float4* tmr4 = (const float4*)(tmax + ((size_t)m * NI + row) * NGRP);
    float4 t0 = tmr4[lane];
    float4 t1 = tmr4[64 + lane];
    unsigned int uv[8] = {umap(t0.x), umap(t0.y), umap(t0.z), umap(t0.w),
                          umap(t1.x), umap(t1.y), umap(t1.z), umap(t1.w)};
    unsigned long long blo = 0, bhi = 0x100000000ull;
    unsigned int taub = 0;
    for (int it = 0; it < 34; ++it) {
      unsigned int mid = (unsigned int)((blo + bhi) >> 1);
      int cnt = 0;
#pragma unroll
      for (int j = 0; j < 8; ++j) cnt += __popcll(__ballot(uv[j] >= mid));
      if (cnt >= 12) {
        taub = mid;
        if (cnt <= MAXSEL) break;
        blo = (unsigned long long)mid + 1;
      } else {
        bhi = mid;
      }
      if (blo >= bhi) break;
    }
    unsigned long long bj[8];
    int base[8];
    int tot = 0;
#pragma unroll
    for (int j = 0; j < 8; ++j) {
      bj[j] = __ballot(uv[j] >= taub);
      base[j] = tot;
      tot += __popcll(bj[j]);
    }
    if (lane < MAXSEL) ssel[lane] = -1;
    unsigned long long ltm = (1ull << lane) - 1ull;
#pragma unroll
    for (int j = 0; j < 8; ++j) {
      if (uv[j] >= taub) {
        int pos = base[j] + __popcll(bj[j] & ltm);
        if (pos < MAXSEL) {
          int g = (j < 4) ? (lane * 4 + j) : (256 + lane * 4 + (j - 4));
          ssel[pos] = g;
        }
      }
    }
  }
  __syncthreads();
  for (int it = 0; it < MAXSEL; ++it) {
    int gsel = ssel[it];
    bool valid = (gsel >= 0);
    int c = valid ? (gsel * 16 + grp) : 0;
    float4 x4 = ((const float4*)(xn + (size_t)c * 64))[l16];
    float s = rq.x * x4.x + rq.y * x4.y + rq.z * x4.z + rq.w * x4.w;
    s += __shfl_xor(s, 1);
    s += __shfl_xor(s, 2);
    s += __shfl_xor(s, 4);
    s += __shfl_xor(s, 8);
    if (l16 == 0) {
      sval[it * 16 + grp] = valid ? s : -3.0e38f;
      scol[it * 16 + grp] = valid ? c : 0x7fffffff;
    }
  }
  __syncthreads();
  if (tid < 64) {
    const int lane = tid;
    float fv[4];
    int fc[4];
    unsigned int uv4[4];
#pragma unroll
    for (int k = 0; k < 4; ++k) {
      fv[k] = sval[lane + 64 * k];
      fc[k] = scol[lane + 64 * k];
      uv4[k] = umap(fv[k]);
    }
    unsigned long long blo = 0, bhi = 0x100000000ull;
    unsigned int taub = 0;
    for (int it = 0; it < 34; ++it) {
      unsigned int mid = (unsigned int)((blo + bhi) >> 1);
      int cnt = 0;
#pragma unroll
      for (int k = 0; k < 4; ++k) cnt += __popcll(__ballot(uv4[k] >= mid));
      if (cnt >= TOPK) {
        taub = mid;
        if (cnt == TOPK) break;
        blo = (unsigned long long)mid + 1;
      } else {
        bhi = mid;
      }
      if (blo >= bhi) break;
    }
    unsigned long long bk[4];
    int base[4];
    int tot = 0;
#pragma unroll
    for (int k = 0; k < 4; ++k) {
      bk[k] = __ballot(uv4[k] >= taub);
      base[k] = tot;
      tot += __popcll(bk[k]);
    }
    float* tv = m ? tkvT : tkvV;
    int* ti = m ? tkiT : tkiV;
    unsigned long long ltm = (1ull << lane) - 1ull;
    if (tot == TOPK) {
#pragma unroll
      for (int k = 0; k < 4; ++k) {
        if (uv4[k] >= taub) {
          int pos = base[k] + __popcll(bk[k] & ltm);
          tv[(size_t)row * TOPK + pos] = fv[k];
          ti[(size_t)row * TOPK + pos] = fc[k];
        }
      }
    } else {
#pragma unroll
      for (int k = 0; k < 4; ++k) {
        if (uv4[k] >= taub) {
          int pos = base[k] + __popcll(bk[k] & ltm);
          if (pos < 32) { lv[pos] = fv[k]; lc[pos] = fc[k]; }
        }
      }
      if (lane == 0) lnum = (tot < 32) ? tot : 32;
      if (lane == 0) {
        int n = lnum;
        unsigned int used = 0;
        for (int q = 0; q < TOPK; ++q) {
          float bv = -3.0e38f;
          int bc = 0x7fffffff, bi = -1;
          for (int i2 = 0; i2 < n; ++i2) {
            if (used & (1u << i2)) continue;
            if (lv[i2] > bv || (lv[i2] == bv && lc[i2] < bc)) {
              bv = lv[i2]; bc = lc[i2]; bi = i2;
            }
          }
          used |= (1u << bi);
          tv[(size_t)row * TOPK + q] = bv;
          ti[(size_t)row * TOPK + q] = bc;
        }
      }
    }
  }
}

// dis[r]: d = w0*sum(topk_v)+w1*sum(topk_t)
__global__ void dis_kernel(const float* __restrict__ tkv_v, const float* __restrict__ tkv_t,
                           const float* __restrict__ iw, float* __restrict__ dis) {
  int r = blockIdx.x * blockDim.x + threadIdx.x;
  if (r >= NI) return;
  float ea = expf(iw[0]), eb = expf(iw[1]);
  float w0 = ea / (ea + eb), w1 = eb / (ea + eb);
  float s0 = 0.f, s1 = 0.f;
  for (int j = 0; j < TOPK; ++j) { s0 += tkv_v[r * TOPK + j]; s1 += tkv_t[r * TOPK + j]; }
  float d = w0 * s0 + w1 * s1;
  dis[r] = (d > 0.0f) ? (1.0f / sqrtf(d)) : 0.0f;
}

// ---------------- fused: item_emb ∪ segsum(layer1) ----------------
__global__ __launch_bounds__(256) void fused_item_segsum_kernel(
    const float* __restrict__ Gi,
    const float* __restrict__ tkv_v, const int* __restrict__ tki_v,
    const float* __restrict__ tkv_t, const int* __restrict__ tki_t,
    const float* __restrict__ dis, const int* __restrict__ ocols,
    const float* __restrict__ ow, const int* __restrict__ ocnt,
    const float* __restrict__ iw, float* __restrict__ nitem,
    const float* __restrict__ Gu, const int* __restrict__ row_ptr,
    const int* __restrict__ csr, float* __restrict__ e1b) {
  const int tid = threadIdx.x;
  const int d = tid & 63;
  if (blockIdx.x >= 2048) {
    const int row = (blockIdx.x - 2048) * 4 + (tid >> 6);
    int a = row_ptr[row], bnd = row_ptr[row + 1];
    float acc = 0.0f;
    for (int e = a; e < bnd; ++e) {
      int s = csr[e];
      const float* sp = (s < NU) ? (Gu + (size_t)s * 64) : (Gi + (size_t)(s - NU) * 64);
      acc += sp[d];
    }
    float ss = warp64_sum(acc * acc);
    float nr = sqrtf(ss);
    e1b[(size_t)row * 64 + d] = acc / fmaxf(nr, 1e-12f);
    return;
  }
  const int row = blockIdx.x * 4 + (tid >> 6);
  float ea = expf(iw[0]), eb = expf(iw[1]);
  float w0 = ea / (ea + eb), w1 = eb / (ea + eb);
  float disr = dis[row];
  float acc = 0.0f;
#pragma unroll 1
  for (int m = 0; m < 2; ++m) {
    const float* tv = m ? tkv_t : tkv_v;
    const int* ti = m ? tki_t : tki_v;
    float wm = (m ? w1 : w0) * 0.3f * disr;
    for (int j = 0; j < TOPK; ++j) {
      float val = tv[(size_t)row * TOPK + j];
      int c = ti[(size_t)row * TOPK + j];
      acc += wm * val * dis[c] * Gi[(size_t)c * 64 + d];
    }
  }
  int cn = ocnt[row];
  for (int j = 0; j < cn; ++j) {
    int c = ocols[(size_t)row * OCAP + j];
    float wv = ow[(size_t)row * OCAP + j];
    acc += wv * Gi[(size_t)c * 64 + d];
  }
  float ss = warp64_sum(acc * acc);
  float nr = sqrtf(ss);
  nitem[(size_t)row * 64 + d] = acc / fmaxf(nr, 1e-12f);
}

// layer-2 agg fused with final combine
__global__ __launch_bounds__(256) void segsum_final_kernel(
    const float* __restrict__ e1b, const int* __restrict__ row_ptr,
    const int* __restrict__ csr, const float* __restrict__ Gu,
    const float* __restrict__ Gi, const float* __restrict__ nitem,
    float* __restrict__ outp) {
  const int d = threadIdx.x & 63;
  const int row = blockIdx.x * 4 + (threadIdx.x >> 6);
  const float* inU = e1b;
  const float* inI = e1b + (size_t)NU * 64;
  int a = row_ptr[row], bnd = row_ptr[row + 1];
  float acc = 0.0f;
  for (int e = a; e < bnd; ++e) {
    int s = csr[e];
    const float* sp = (s < NU) ? (inU + (size_t)s * 64) : (inI + (size_t)(s - NU) * 64);
    acc += sp[d];
  }
  float ss = warp64_sum(acc * acc);
  float e2 = acc / fmaxf(sqrtf(ss), 1e-12f);
  float base = (row < NU) ? Gu[(size_t)row * 64 + d] : Gi[(size_t)(row - NU) * 64 + d];
  float v = (base + e1b[(size_t)row * 64 + d] + e2) * (1.0f / 3.0f);
  if (row >= NU) v += nitem[(size_t)(row - NU) * 64 + d];
  outp[(size_t)row * 64 + d] = v;
}

extern "C" void kernel_launch(void* const* d_in, const int* in_sizes, int n_in,
                              void* d_out, int out_size, void* d_ws, size_t ws_size,
                              hipStream_t stream) {
  const float* Gu = (const float*)d_in[0];
  const float* Gi = (const float*)d_in[1];
  const float* feat_v = (const float*)d_in[2];
  const float* feat_t = (const float*)d_in[3];
  const float* W_v = (const float*)d_in[4];
  const float* b_v = (const float*)d_in[5];
  const float* W_t = (const float*)d_in[6];
  const float* b_t = (const float*)d_in[7];
  const float* iw = (const float*)d_in[8];
  const float* Sv = (const float*)d_in[9];
  const float* St = (const float*)d_in[10];
  const int* eidx = (const int*)d_in[11];
  const int twoE = in_sizes[11] / 2;  // 1048576 directed edges
  const int* esrc = eidx;
  const int* edst = eidx + twoE;
  float* outp = (float*)d_out;

  char* w = (char*)d_ws;
  size_t off = 0;
  auto alloc = [&](size_t bytes) -> void* {
    void* p = w + off;
    off = (off + bytes + 255) & ~(size_t)255;
    return p;
  };
  float* xn_v = (float*)alloc((size_t)NI * 64 * 4);
  float* xn_t = (float*)alloc((size_t)NI * 64 * 4);
  ushort* hiV = (ushort*)alloc((size_t)NI * 64 * 2);
  ushort* loV = (ushort*)alloc((size_t)NI * 64 * 2);
  ushort* hiT = (ushort*)alloc((size_t)NI * 64 * 2);
  ushort* loT = (ushort*)alloc((size_t)NI * 64 * 2);
  float* tmax = (float*)alloc((size_t)2 * NI * NGRP * 4);  // 32 MB
  float* tkvV = (float*)alloc((size_t)NI * TOPK * 4);
  int* tkiV = (int*)alloc((size_t)NI * TOPK * 4);
  float* tkvT = (float*)alloc((size_t)NI * TOPK * 4);
  int* tkiT = (int*)alloc((size_t)NI * TOPK * 4);
  float* dis = (float*)alloc((size_t)NI * 4);
  int* ocols = (int*)alloc((size_t)NI * OCAP * 4);
  float* ow = (float*)alloc((size_t)NI * OCAP * 4);
  int* ocnt = (int*)alloc((size_t)NI * 4);
  float* nitem = (float*)alloc((size_t)NI * 64 * 4);
  float* e1b = (float*)alloc((size_t)NTOT * 64 * 4);
  int* deg = (int*)alloc((size_t)NTOT * 4);
  int* row_ptr = (int*)alloc((size_t)(NTOT + 1) * 4);
  int* cursor = (int*)alloc((size_t)NTOT * 4);
  int* csr = (int*)alloc((size_t)twoE * 4);
  int* locb = (int*)alloc((size_t)NTOT * 4);
  int* bsum = (int*)alloc((size_t)(NTOT / 256) * 4);
  if (off > ws_size) return;

  // k-split partial buffers alias tmax (consumed before tilemax writes it)
  float* partialV = tmax;
  float* partialT = tmax + (size_t)8 * NI * 64;

  hipMemsetAsync(deg, 0, (size_t)NTOT * 4, stream);

  // proj_v GEMM (first) ∪ edge histogram (backfills)
  fused_proj_hist_kernel<<<1024 + 4096, 256, 0, stream>>>(
      feat_v, W_v, partialV, 4096, 512, edst, deg, twoE);
  // proj_t GEMM (first) ∪ proj_reduce_v ∪ scanA
  fused_projT_reduceV_scanA_kernel<<<768 + 2048 + 96, 256, 0, stream>>>(
      feat_t, W_t, partialT, partialV, b_v, xn_v, hiV, loV, deg, locb, bsum);
  // proj_reduce_t (first) ∪ scanC
  fused_reduceT_scanC_kernel<<<2048 + 97, 256, 0, stream>>>(
      partialT, b_t, xn_t, hiT, loT, locb, bsum, row_ptr, cursor, NTOT);
  // tilemax standalone at full occupancy (2048 blocks)
  sim_tilemax_kernel<<<2048, 256, 0, stream>>>(hiV, loV, hiT, loT, tmax);
  // scan_sim ∥ rescore (1:8 bid interleave) ∪ fill
  fused_scan_rescore_fill_kernel<<<18432 + 4096, 256, 0, stream>>>(
      Sv, St, iw, ocols, ow, ocnt, xn_v, xn_t, tmax, tkvV, tkiV, tkvT, tkiT,
      esrc, edst, cursor, csr, twoE);
  dis_kernel<<<(NI + 255) / 256, 256, 0, stream>>>(tkvV, tkvT, iw, dis);
  // item_emb (first) ∪ segsum layer-1
  fused_item_segsum_kernel<<<2048 + NTOT / 4, 256, 0, stream>>>(
      Gi, tkvV, tkiV, tkvT, tkiT, dis, ocols, ow, ocnt, iw, nitem,
      Gu, row_ptr, csr, e1b);
  segsum_final_kernel<<<NTOT / 4, 256, 0, stream>>>(e1b, row_ptr, csr, Gu, Gi, nitem, outp);
}